// Round 13
// baseline (404.385 us; speedup 1.0000x reference)
//
#include <hip/hip_runtime.h>
#include <stdint.h>

typedef __attribute__((ext_vector_type(4))) float f32x4;
typedef __attribute__((ext_vector_type(8))) __bf16 bf16x8;
typedef __attribute__((ext_vector_type(4))) unsigned int u32x4;
typedef __attribute__((ext_vector_type(4))) int i32x4;

#define DEV static __device__ __forceinline__

DEV float bf2f(unsigned short h){ union{unsigned int u; float f;} v; v.u=((unsigned int)h)<<16; return v.f; }
DEV unsigned short f2bf(float f){ union{float ff; unsigned int u;} v; v.ff=f; unsigned int u=v.u;
  u += 0x7fffu + ((u>>16)&1u); return (unsigned short)(u>>16); }

DEV f32x4 mfma16(bf16x8 a, bf16x8 b, f32x4 c){
  return __builtin_amdgcn_mfma_f32_16x16x32_bf16(a, b, c, 0, 0, 0);
}
DEV i32x4 mfma_i8(i32x4 a, i32x4 b, i32x4 c){
  return __builtin_amdgcn_mfma_i32_16x16x64_i8(a, b, c, 0, 0, 0);
}

// async global->LDS, 16B per lane; lds dest = wave-uniform base + lane*16B
#define GLOAD_LDS16(gptr, ldsptr) \
  __builtin_amdgcn_global_load_lds( \
      (const __attribute__((address_space(1))) unsigned int*)(gptr), \
      (__attribute__((address_space(3))) unsigned int*)(ldsptr), 16, 0, 0)

// ---------------- weight sign-quantization (int8) + |w| partial sums ----------------
__global__ __launch_bounds__(256) void k_quant_w(
    const float* __restrict__ wq, const float* __restrict__ wg, const float* __restrict__ wp,
    signed char* __restrict__ oq, signed char* __restrict__ og, signed char* __restrict__ op,
    float* __restrict__ partials)
{
  int blk = blockIdx.x, t = threadIdx.x;
  const float* src; signed char* dst; long base;
  if (blk < 3072){ src=wq; dst=oq; base=(long)blk*4096; }
  else if (blk < 4096){ src=wg; dst=og; base=(long)(blk-3072)*4096; }
  else { src=wp; dst=op; base=(long)(blk-4096)*4096; }
  float s = 0.f;
  #pragma unroll
  for (int i=0;i<4;i++){
    long e = base + (long)(i*256 + t)*4;
    float4 v = *reinterpret_cast<const float4*>(src + e);
    s += fabsf(v.x)+fabsf(v.y)+fabsf(v.z)+fabsf(v.w);
    signed char tmp[4];
    tmp[0] = (v.x>0.f)?1:((v.x<0.f)?-1:0);
    tmp[1] = (v.y>0.f)?1:((v.y<0.f)?-1:0);
    tmp[2] = (v.z>0.f)?1:((v.z<0.f)?-1:0);
    tmp[3] = (v.w>0.f)?1:((v.w<0.f)?-1:0);
    *reinterpret_cast<unsigned int*>(dst + e) = *reinterpret_cast<unsigned int*>(tmp);
  }
  #pragma unroll
  for (int m=1;m<64;m<<=1) s += __shfl_xor(s, m);
  __shared__ float red[4];
  if ((t&63)==0) red[t>>6]=s;
  __syncthreads();
  if (t==0) partials[blk] = red[0]+red[1]+red[2]+red[3];
}

__global__ void k_finalize(const float* __restrict__ partials, float* __restrict__ scales)
{
  int t = threadIdx.x;
  __shared__ float red[4];
  for (int w=0; w<3; w++){
    int s0 = (w==0)?0:((w==1)?3072:4096);
    int s1 = (w==0)?3072:((w==1)?4096:5120);
    float acc = 0.f;
    for (int i=s0+t; i<s1; i+=256) acc += partials[i];
    #pragma unroll
    for (int m=1;m<64;m<<=1) acc += __shfl_xor(acc, m);
    if ((t&63)==0) red[t>>6]=acc;
    __syncthreads();
    if (t==0){
      float total = red[0]+red[1]+red[2]+red[3];
      float denom = (w==0)? 12582912.0f : 4194304.0f;
      float wsc = fmaxf(total/denom, 1e-5f);
      scales[w] = wsc / 127.0f;           // folded w_scale/127
    }
    __syncthreads();
  }
}

// ---------------- activation quantization -> int8 ----------------
__global__ __launch_bounds__(256) void k_quant_x(const float* __restrict__ x,
    signed char* __restrict__ xq, float* __restrict__ xs)
{
  int row=blockIdx.x, t=threadIdx.x;
  const float* xr = x + (long)row*2048;
  float v[8];
  float4 a = *reinterpret_cast<const float4*>(xr + t*8);
  float4 b = *reinterpret_cast<const float4*>(xr + t*8 + 4);
  v[0]=a.x; v[1]=a.y; v[2]=a.z; v[3]=a.w; v[4]=b.x; v[5]=b.y; v[6]=b.z; v[7]=b.w;
  float mx=0.f;
  #pragma unroll
  for (int j=0;j<8;j++) mx = fmaxf(mx, fabsf(v[j]));
  #pragma unroll
  for (int m=1;m<64;m<<=1) mx = fmaxf(mx, __shfl_xor(mx, m));
  __shared__ float red[4];
  if ((t&63)==0) red[t>>6]=mx;
  __syncthreads();
  float sc = fmaxf(fmaxf(fmaxf(red[0],red[1]),fmaxf(red[2],red[3])), 1e-5f);
  if (t==0) xs[row]=sc;
  signed char q[8];
  #pragma unroll
  for (int j=0;j<8;j++) q[j] = (signed char)(int)rintf((v[j]/sc)*127.f);
  *reinterpret_cast<uint2*>(xq + (long)row*2048 + t*8) = *reinterpret_cast<uint2*>(q);
}

// ---------------- bitlinear GEMM, i8 MFMA, 256x256 tile, BK=128, 8 waves (2x4) ----------------
// round-8-proven pipeline: stage tile t+1 (8 gloads/wave), vmcnt(8), raw barrier,
// 2x(12 ds_read + 32 MFMA), trailing barrier. Both-sides granule-XOR swizzle.
// XCD-chunked + 8x8 super-tile swizzle for L2.
// MODE 0: merged qkv+gate (cols 0..6143 qkv, 6144..8191 gate/decay); MODE 2: proj -> f32
template<int MODE, int NBN>
__global__ __launch_bounds__(512, 1) void k_gemm(
    const signed char* __restrict__ A, const signed char* __restrict__ Bw,
    const float* __restrict__ xs, const float* __restrict__ scales,
    const float* __restrict__ bias0, const float* __restrict__ bias1,
    unsigned short* __restrict__ oq, unsigned short* __restrict__ ok, unsigned short* __restrict__ ov,
    float* __restrict__ decay, float* __restrict__ of32)
{
  __shared__ signed char As[2][256*128];
  __shared__ signed char Bs[2][256*128];
  const int K = 2048, NT = 16;          // K-tiles of 128
  int tid=threadIdx.x;
  // block swizzle: XCD-contiguous chunks, then 8x8 (bn,bm) super-tiles
  const int nwg = NBN*32, cpx = nwg>>3;
  int wg  = ((int)blockIdx.x & 7)*cpx + ((int)blockIdx.x >> 3);
  int super = wg >> 6, inner = wg & 63;
  int bn = (super % (NBN>>3))*8 + (inner & 7);
  int bm = (super / (NBN>>3))*8 + (inner >> 3);
  long n0=(long)bn*256, m0=(long)bm*256;
  int wave=tid>>6, lane=tid&63, l15=lane&15, l4=lane>>4;
  int wm=wave>>2, wn=wave&3;            // wave owns rows wm*128..+128, cols wn*64..+64
  int srow = wave*32 + (lane>>3);       // staging row base; (row&7)==(lane>>3)
  int scol = ((lane&7) ^ (lane>>3))*16; // pre-swizzled source col (bytes)
  i32x4 z4 = {0,0,0,0};
  i32x4 acc[8][4];
  #pragma unroll
  for (int i=0;i<8;i++)
    #pragma unroll
    for (int j=0;j<4;j++) acc[i][j]=z4;

#define STAGE_ALL(buf, kt) do{ \
    GLOAD_LDS16(A  + (m0 + srow +  0)*K + (kt) + scol, &As[buf][(wave*32 +  0)*128]); \
    GLOAD_LDS16(A  + (m0 + srow +  8)*K + (kt) + scol, &As[buf][(wave*32 +  8)*128]); \
    GLOAD_LDS16(A  + (m0 + srow + 16)*K + (kt) + scol, &As[buf][(wave*32 + 16)*128]); \
    GLOAD_LDS16(A  + (m0 + srow + 24)*K + (kt) + scol, &As[buf][(wave*32 + 24)*128]); \
    GLOAD_LDS16(Bw + (n0 + srow +  0)*K + (kt) + scol, &Bs[buf][(wave*32 +  0)*128]); \
    GLOAD_LDS16(Bw + (n0 + srow +  8)*K + (kt) + scol, &Bs[buf][(wave*32 +  8)*128]); \
    GLOAD_LDS16(Bw + (n0 + srow + 16)*K + (kt) + scol, &Bs[buf][(wave*32 + 16)*128]); \
    GLOAD_LDS16(Bw + (n0 + srow + 24)*K + (kt) + scol, &Bs[buf][(wave*32 + 24)*128]); }while(0)
// fragment: row base multiple of 16 -> (row&7)==(l15&7); granule pos = G ^ (row&7)
#define RD_A(buf, mi, kk) (*reinterpret_cast<const i32x4*>(&As[buf][(wm*128+(mi)*16+l15)*128 + ((((kk)*4+l4) ^ (l15&7))<<4)]))
#define RD_B(buf, ni, kk) (*reinterpret_cast<const i32x4*>(&Bs[buf][(wn*64 +(ni)*16+l15)*128 + ((((kk)*4+l4) ^ (l15&7))<<4)]))

  // prologue: stage tile 0 -> buf 0
  STAGE_ALL(0, 0);

  for (int t=0; t<NT; ++t){
    int c = t&1;
    if (t+1 < NT){
      STAGE_ALL(c^1, (t+1)*128);
      asm volatile("s_waitcnt vmcnt(8)" ::: "memory");  // tile t landed; t+1 in flight
    } else {
      asm volatile("s_waitcnt vmcnt(0)" ::: "memory");
    }
    __builtin_amdgcn_s_barrier();
    __builtin_amdgcn_s_setprio(1);
    #pragma unroll
    for (int kk=0;kk<2;kk++){
      i32x4 af[8], bfr[4];
      #pragma unroll
      for (int mi=0;mi<8;mi++) af[mi] = RD_A(c,mi,kk);
      #pragma unroll
      for (int ni=0;ni<4;ni++) bfr[ni] = RD_B(c,ni,kk);
      #pragma unroll
      for (int mi=0;mi<8;mi++)
        #pragma unroll
        for (int ni=0;ni<4;ni++)
          acc[mi][ni] = mfma_i8(af[mi], bfr[ni], acc[mi][ni]);
    }
    __builtin_amdgcn_s_setprio(0);
    if (t+1 < NT) __builtin_amdgcn_s_barrier();   // buf c free for next stage
  }

  if (MODE==0 && bn < 24){
    float fac = scales[0];
    float xsv[8][4];
    #pragma unroll
    for (int mi=0;mi<8;mi++)
      #pragma unroll
      for (int r2=0;r2<4;r2++)
        xsv[mi][r2] = xs[m0 + wm*128 + mi*16 + 4*l4 + r2] * fac;
    int sidx = (int)(n0 >> 11);
    unsigned short* dst = (sidx==0)?oq:((sidx==1)?ok:ov);
    int c0 = (int)(n0 & 2047);
    #pragma unroll
    for (int ni=0;ni<4;ni++){
      int c = c0 + wn*64 + ni*16 + l15;
      float bv = bias0[n0 + wn*64 + ni*16 + l15];
      #pragma unroll
      for (int mi=0;mi<8;mi++)
        #pragma unroll
        for (int r2=0;r2<4;r2++){
          long grow = m0 + wm*128 + mi*16 + 4*l4 + r2;
          dst[grow*2048 + c] = f2bf((float)acc[mi][ni][r2]*xsv[mi][r2] + bv);
        }
    }
  } else if (MODE==0){
    // gate: this wave's 128 rows = exactly one chunk
    float fac = scales[1];
    float xsv[8][4];
    #pragma unroll
    for (int mi=0;mi<8;mi++)
      #pragma unroll
      for (int r2=0;r2<4;r2++)
        xsv[mi][r2] = xs[m0 + wm*128 + mi*16 + 4*l4 + r2] * fac;
    long row0 = m0 + wm*128;
    int b = (int)(row0>>12), ch = (int)((row0>>7)&31);
    #pragma unroll
    for (int ni=0;ni<4;ni++){
      long cg = n0 + wn*64 + ni*16 + l15;
      long g = cg - 6144;
      float bv = bias1[g];
      float ssum = 0.f;
      #pragma unroll
      for (int mi=0;mi<8;mi++)
        #pragma unroll
        for (int r2=0;r2<4;r2++){
          float val = (float)acc[mi][ni][r2]*xsv[mi][r2] + bv;
          ssum += 1.f/(1.f + expf(-val));
        }
      ssum += __shfl_xor(ssum, 16);
      ssum += __shfl_xor(ssum, 32);
      if (l4==0){
        int h = (int)(g>>7), d = (int)(g&127);
        decay[((long)(b*32+ch)*16 + h)*128 + d] = ssum*(1.0f/128.0f);
      }
    }
  } else {
    float fac = scales[2];
    float xsv[8][4];
    #pragma unroll
    for (int mi=0;mi<8;mi++)
      #pragma unroll
      for (int r2=0;r2<4;r2++)
        xsv[mi][r2] = xs[m0 + wm*128 + mi*16 + 4*l4 + r2] * fac;
    #pragma unroll
    for (int ni=0;ni<4;ni++){
      long c = n0 + wn*64 + ni*16 + l15;
      float bv = bias0[c];
      #pragma unroll
      for (int mi=0;mi<8;mi++)
        #pragma unroll
        for (int r2=0;r2<4;r2++){
          long grow = m0 + wm*128 + mi*16 + 4*l4 + r2;
          of32[grow*2048 + c] = (float)acc[mi][ni][r2]*xsv[mi][r2] + bv;
        }
    }
  }
#undef STAGE_ALL
#undef RD_A
#undef RD_B
}

// ---------------- Phase A: per-token 16x16 HEAD-mixing attention ----------------
__global__ __launch_bounds__(256) void k_attnA(const unsigned short* __restrict__ qb,
    const unsigned short* __restrict__ kb, const unsigned short* __restrict__ vb,
    unsigned short* __restrict__ aof)
{
  __shared__ unsigned short at[4][16*32];    // attn, zero-padded g in [16,32)
  __shared__ unsigned short vT[4][128*40];   // v^T [e][g], row stride 40, zero-padded
  int tid=threadIdx.x, wave=tid>>6, lane=tid&63, l15=lane&15, l4=lane>>4;
  const float SCALE = 0.08838834764831845f;

  for (int i=lane;i<16*32;i+=64) at[wave][i]=0;
  for (int i=lane;i<128*40;i+=64) vT[wave][i]=0;

  long token = (long)blockIdx.x*4 + wave;
  long base = token*2048;

  bf16x8 qf[4], kf[4];
  #pragma unroll
  for (int kk=0;kk<4;kk++){
    qf[kk] = *reinterpret_cast<const bf16x8*>(qb + base + l15*128 + kk*32 + l4*8);
    kf[kk] = *reinterpret_cast<const bf16x8*>(kb + base + l15*128 + kk*32 + l4*8);
  }
  {
    int g = lane>>2, e0 = (lane&3)*32;
    #pragma unroll
    for (int j=0;j<4;j++){
      u32x4 vv = *reinterpret_cast<const u32x4*>(vb + base + g*128 + e0 + j*8);
      unsigned short tmp[8];
      *reinterpret_cast<u32x4*>(tmp) = vv;
      #pragma unroll
      for (int t2=0;t2<8;t2++) vT[wave][(e0+j*8+t2)*40 + g] = tmp[t2];
    }
  }

  f32x4 s = {0.f,0.f,0.f,0.f};
  #pragma unroll
  for (int kk=0;kk<4;kk++) s = mfma16(qf[kk], kf[kk], s);

  #pragma unroll
  for (int r2=0;r2<4;r2++){
    float v = s[r2];
    float m = v;
    m = fmaxf(m, __shfl_xor(m,1)); m = fmaxf(m, __shfl_xor(m,2));
    m = fmaxf(m, __shfl_xor(m,4)); m = fmaxf(m, __shfl_xor(m,8));
    float p = expf((v-m)*SCALE);
    float sum = p;
    sum += __shfl_xor(sum,1); sum += __shfl_xor(sum,2);
    sum += __shfl_xor(sum,4); sum += __shfl_xor(sum,8);
    at[wave][(4*l4+r2)*32 + l15] = f2bf(p/sum);
  }
  __syncthreads();

  bf16x8 pa = *reinterpret_cast<const bf16x8*>(&at[wave][l15*32 + l4*8]);
  #pragma unroll
  for (int eb=0;eb<8;eb++){
    bf16x8 vf = *reinterpret_cast<const bf16x8*>(&vT[wave][(eb*16+l15)*40 + l4*8]);
    f32x4 z4 = {0.f,0.f,0.f,0.f};
    f32x4 o = mfma16(pa, vf, z4);
    #pragma unroll
    for (int r2=0;r2<4;r2++)
      aof[base + (long)(4*l4+r2)*128 + eb*16 + l15] = f2bf(o[r2]);
  }
}

// ---------------- Phase B1: per-chunk kv-update upd[e][d] = v^T . k ----------------
__global__ __launch_bounds__(256) void k_updB1(
    const unsigned short* __restrict__ kb, const unsigned short* __restrict__ vb,
    float* __restrict__ upds)
{
  __shared__ unsigned short kT[128*128];
  __shared__ unsigned short vT[128*128];
  int bid=blockIdx.x;
  int ch = bid&31, h=(bid>>5)&15, b=bid>>9;
  int tid=threadIdx.x, wave=tid>>6, lane=tid&63, l15=lane&15, l4=lane>>4;
  long base = ((long)b*4096 + (long)ch*128)*2048 + h*128;

  #pragma unroll
  for (int i=0;i<8;i++){
    int s = tid + i*256;
    int l = s>>4, sl = s&15;
    unsigned short tmp[8];
    u32x4 v1 = *reinterpret_cast<const u32x4*>(kb + base + (long)l*2048 + sl*8);
    *reinterpret_cast<u32x4*>(tmp) = v1;
    #pragma unroll
    for (int j=0;j<8;j++){
      int d = sl*8+j;
      kT[d*128 + (((l>>3)^(d&15))<<3) + (l&7)] = tmp[j];
    }
    u32x4 v2 = *reinterpret_cast<const u32x4*>(vb + base + (long)l*2048 + sl*8);
    *reinterpret_cast<u32x4*>(tmp) = v2;
    #pragma unroll
    for (int j=0;j<8;j++){
      int e = sl*8+j;
      vT[e*128 + (((l>>3)^(e&15))<<3) + (l&7)] = tmp[j];
    }
  }
  __syncthreads();

  f32x4 z4 = {0.f,0.f,0.f,0.f};
  f32x4 acc[2][8];
  #pragma unroll
  for (int er=0;er<2;er++)
    #pragma unroll
    for (int dc=0;dc<8;dc++) acc[er][dc]=z4;

  #pragma unroll
  for (int kk=0;kk<4;kk++){
    bf16x8 xf[2];
    #pragma unroll
    for (int er=0;er<2;er++){
      int e = wave*32 + er*16 + l15;
      xf[er] = *reinterpret_cast<const bf16x8*>(vT + e*128 + (((kk*4+l4)^(e&15))<<3));
    }
    #pragma unroll
    for (int dc=0;dc<8;dc++){
      int d = dc*16 + l15;
      bf16x8 kf = *reinterpret_cast<const bf16x8*>(kT + d*128 + (((kk*4+l4)^(d&15))<<3));
      #pragma unroll
      for (int er=0;er<2;er++)
        acc[er][dc] = mfma16(xf[er], kf, acc[er][dc]);
    }
  }

  float* dst = upds + (long)bid*16384;
  #pragma unroll
  for (int er=0;er<2;er++)
    #pragma unroll
    for (int dc=0;dc<8;dc++)
      #pragma unroll
      for (int r2=0;r2<4;r2++){
        int e = wave*32 + er*16 + 4*l4 + r2;
        int d = dc*16 + l15;
        dst[e*128 + d] = acc[er][dc][r2];
      }
}

// ---------------- Phase B2: in-place elementwise scan over chunks ----------------
__global__ __launch_bounds__(256) void k_scanB2(float* __restrict__ buf,
    const float* __restrict__ decay)
{
  int bid=blockIdx.x;
  int strip = bid&7, bh = bid>>3;
  int b = bh>>4, h = bh&15;
  int t = threadIdx.x;
  int f0 = t, f1 = t + 256;
  int e0 = strip*16 + (f0>>5), d0 = (f0&31)*4;
  int e1 = strip*16 + (f1>>5);
  long base = (long)bh * 32 * 16384;
  long o0 = (long)e0*128 + d0;
  long o1 = (long)e1*128 + d0;
  float4 s0 = {0.f,0.f,0.f,0.f}, s1 = {0.f,0.f,0.f,0.f};
  for (int ch=0; ch<32; ch++){
    float* p = buf + base + (long)ch*16384;
    float4 u0 = *reinterpret_cast<float4*>(p + o0);
    float4 u1 = *reinterpret_cast<float4*>(p + o1);
    *reinterpret_cast<float4*>(p + o0) = s0;
    *reinterpret_cast<float4*>(p + o1) = s1;
    float4 dc = *reinterpret_cast<const float4*>(decay + ((long)(b*32+ch)*16 + h)*128 + d0);
    s0.x = s0.x*dc.x + u0.x; s0.y = s0.y*dc.y + u0.y;
    s0.z = s0.z*dc.z + u0.z; s0.w = s0.w*dc.w + u0.w;
    s1.x = s1.x*dc.x + u1.x; s1.y = s1.y*dc.y + u1.y;
    s1.z = s1.z*dc.z + u1.z; s1.w = s1.w*dc.w + u1.w;
  }
}

// ---------------- Phase B3: recur[l][e] = q . state[e][:], hi/lo split, RMW aof ----------------
__global__ __launch_bounds__(256) void k_recurB3(
    const unsigned short* __restrict__ qb, const float* __restrict__ upds,
    unsigned short* __restrict__ aof)
{
  __shared__ unsigned short sh[128*128];
  __shared__ unsigned short slo[128*128];
  int bid=blockIdx.x;
  int ch = bid&31, h=(bid>>5)&15, b=bid>>9;
  int tid=threadIdx.x, wave=tid>>6, lane=tid&63, l15=lane&15, l4=lane>>4;
  long slab = (long)bid*16384;
  long base = ((long)b*4096 + (long)ch*128)*2048 + h*128;

  #pragma unroll
  for (int i=0;i<8;i++){
    int s = tid + i*256;
    int e = s>>4, sl = s&15;
    float4 a = *reinterpret_cast<const float4*>(upds + slab + (long)e*128 + sl*8);
    float4 c = *reinterpret_cast<const float4*>(upds + slab + (long)e*128 + sl*8 + 4);
    float vv[8] = {a.x,a.y,a.z,a.w,c.x,c.y,c.z,c.w};
    unsigned short hi[8], lo[8];
    #pragma unroll
    for (int j=0;j<8;j++){
      hi[j] = f2bf(vv[j]);
      lo[j] = f2bf(vv[j] - bf2f(hi[j]));
    }
    int slot = e*128 + ((sl ^ (e&15))<<3);
    *reinterpret_cast<u32x4*>(sh + slot)  = *reinterpret_cast<u32x4*>(hi);
    *reinterpret_cast<u32x4*>(slo + slot) = *reinterpret_cast<u32x4*>(lo);
  }

  bf16x8 qf[2][4];
  #pragma unroll
  for (int mr=0;mr<2;mr++)
    #pragma unroll
    for (int kk=0;kk<4;kk++)
      qf[mr][kk] = *reinterpret_cast<const bf16x8*>(qb + base + (long)(wave*32+mr*16+l15)*2048 + kk*32 + l4*8);
  __syncthreads();

  f32x4 z4 = {0.f,0.f,0.f,0.f};
  f32x4 acc[2][8];
  #pragma unroll
  for (int mr=0;mr<2;mr++)
    #pragma unroll
    for (int ec=0;ec<8;ec++) acc[mr][ec]=z4;

  #pragma unroll
  for (int kk=0;kk<4;kk++)
    #pragma unroll
    for (int ec=0;ec<8;ec++){
      int e = ec*16 + l15;
      int slot = (((kk*4+l4)^(e&15))<<3);
      bf16x8 tfh = *reinterpret_cast<const bf16x8*>(sh + e*128 + slot);
      bf16x8 tfl = *reinterpret_cast<const bf16x8*>(slo + e*128 + slot);
      #pragma unroll
      for (int mr=0;mr<2;mr++){
        acc[mr][ec] = mfma16(qf[mr][kk], tfh, acc[mr][ec]);
        acc[mr][ec] = mfma16(qf[mr][kk], tfl, acc[mr][ec]);
      }
    }

  #pragma unroll
  for (int mr=0;mr<2;mr++)
    #pragma unroll
    for (int ec=0;ec<8;ec++)
      #pragma unroll
      for (int r2=0;r2<4;r2++){
        long o = base + (long)(wave*32+mr*16+4*l4+r2)*2048 + ec*16 + l15;
        aof[o] = f2bf(bf2f(aof[o]) + acc[mr][ec][r2]);
      }
}

// ---------------- rmsnorm (bf16 in) + re-quantize -> int8 ----------------
__global__ __launch_bounds__(256) void k_rmsnorm_quant(const unsigned short* __restrict__ ain,
    const float* __restrict__ normw, signed char* __restrict__ x2q, float* __restrict__ xs2)
{
  int row=blockIdx.x, t=threadIdx.x;
  const unsigned short* rp = ain + (long)row*2048;
  u32x4 raw = *reinterpret_cast<const u32x4*>(rp + t*8);
  unsigned short tmp[8];
  *reinterpret_cast<u32x4*>(tmp) = raw;
  float xv[8]; float ss=0.f;
  #pragma unroll
  for (int j=0;j<8;j++){ xv[j]=bf2f(tmp[j]); ss += xv[j]*xv[j]; }
  #pragma unroll
  for (int m=1;m<64;m<<=1) ss += __shfl_xor(ss, m);
  __shared__ float red[4];
  if ((t&63)==0) red[t>>6]=ss;
  __syncthreads();
  float ms = (red[0]+red[1]+red[2]+red[3])*(1.0f/2048.0f) + 1e-6f;
  float rs = 1.0f/sqrtf(ms);
  __syncthreads();
  float4 w0 = *reinterpret_cast<const float4*>(normw + t*8);
  float4 w1 = *reinterpret_cast<const float4*>(normw + t*8 + 4);
  float wv[8] = {w0.x,w0.y,w0.z,w0.w,w1.x,w1.y,w1.z,w1.w};
  float y[8]; float mx=0.f;
  #pragma unroll
  for (int j=0;j<8;j++){ y[j] = xv[j]*rs*wv[j]; mx = fmaxf(mx, fabsf(y[j])); }
  #pragma unroll
  for (int m=1;m<64;m<<=1) mx = fmaxf(mx, __shfl_xor(mx, m));
  __shared__ float red2[4];
  if ((t&63)==0) red2[t>>6]=mx;
  __syncthreads();
  float sc = fmaxf(fmaxf(fmaxf(red2[0],red2[1]),fmaxf(red2[2],red2[3])), 1e-5f);
  if (t==0) xs2[row]=sc;
  signed char q[8];
  #pragma unroll
  for (int j=0;j<8;j++) q[j] = (signed char)(int)rintf((y[j]/sc)*127.f);
  *reinterpret_cast<uint2*>(x2q + (long)row*2048 + t*8) = *reinterpret_cast<uint2*>(q);
}

// ---------------- host launch ----------------
extern "C" void kernel_launch(void* const* d_in, const int* in_sizes, int n_in,
                              void* d_out, int out_size, void* d_ws, size_t ws_size,
                              hipStream_t stream)
{
  const float* x      = (const float*)d_in[0];
  const float* qkv_w  = (const float*)d_in[1];
  const float* qkv_b  = (const float*)d_in[2];
  const float* gate_w = (const float*)d_in[3];
  const float* gate_b = (const float*)d_in[4];
  const float* proj_w = (const float*)d_in[5];
  const float* proj_b = (const float*)d_in[6];
  const float* norm_w = (const float*)d_in[7];
  (void)in_sizes; (void)n_in; (void)out_size; (void)ws_size;

  char* ws = (char*)d_ws;
  const size_t MB = 1024UL*1024UL;
  // wq_qkv and wq_gate CONTIGUOUS (merged GEMM reads rows 0..8191)
  signed char* wq_proj = (signed char*)(ws + 0*MB);   // 4MB, alive to end
  signed char* wq_qkv  = (signed char*)(ws + 4*MB);   // 12MB (rows 0..6143)
  signed char* wq_gate = (signed char*)(ws + 16*MB);  // 4MB  (rows 6144..8191)
  signed char* xq      = (signed char*)(ws + 20*MB);  // 16MB, dies after merged gemm
  float*       upds    = (float*)(ws + 4*MB);         // 64MB f32 (1024 slabs), aliases wq_qkv/gate/xq
  unsigned short* qb   = (unsigned short*)(ws + 68*MB);   // 32MB (x2q aliases after B3)
  unsigned short* kb   = (unsigned short*)(ws + 100*MB);  // 32MB
  unsigned short* vb   = (unsigned short*)(ws + 132*MB);  // 32MB
  unsigned short* aof  = (unsigned short*)(ws + 164*MB);  // 32MB bf16
  signed char* x2q     = (signed char*)qb;
  float* xs       = (float*)(ws + 196*MB);
  float* xs2      = xs + 8192;
  float* decay    = xs2 + 8192;
  float* partials = decay + 131072;
  float* scales   = partials + 5120;

  k_quant_w<<<5120,256,0,stream>>>(qkv_w, gate_w, proj_w, wq_qkv, wq_gate, wq_proj, partials);
  k_finalize<<<1,256,0,stream>>>(partials, scales);
  k_quant_x<<<8192,256,0,stream>>>(x, xq, xs);
  k_gemm<0,32><<<1024,512,0,stream>>>(xq, wq_qkv, xs, scales, qkv_b, gate_b,
      qb,kb,vb, decay, nullptr);
  k_attnA<<<2048,256,0,stream>>>(qb,kb,vb, aof);
  k_updB1<<<1024,256,0,stream>>>(kb, vb, upds);
  k_scanB2<<<256,256,0,stream>>>(upds, decay);
  k_recurB3<<<1024,256,0,stream>>>(qb, upds, aof);
  k_rmsnorm_quant<<<8192,256,0,stream>>>(aof, norm_w, x2q, xs2);
  k_gemm<2,8><<<256,512,0,stream>>>(x2q, wq_proj, xs2, scales, proj_b, nullptr,
      nullptr,nullptr,nullptr, nullptr, (float*)d_out);
}

// Round 14
// 401.961 us; speedup vs baseline: 1.0060x; 1.0060x over previous
//
#include <hip/hip_runtime.h>
#include <stdint.h>

typedef __attribute__((ext_vector_type(4))) float f32x4;
typedef __attribute__((ext_vector_type(8))) __bf16 bf16x8;
typedef __attribute__((ext_vector_type(4))) unsigned int u32x4;
typedef __attribute__((ext_vector_type(4))) int i32x4;

#define DEV static __device__ __forceinline__

DEV float bf2f(unsigned short h){ union{unsigned int u; float f;} v; v.u=((unsigned int)h)<<16; return v.f; }
DEV unsigned short f2bf(float f){ union{float ff; unsigned int u;} v; v.ff=f; unsigned int u=v.u;
  u += 0x7fffu + ((u>>16)&1u); return (unsigned short)(u>>16); }

DEV f32x4 mfma16(bf16x8 a, bf16x8 b, f32x4 c){
  return __builtin_amdgcn_mfma_f32_16x16x32_bf16(a, b, c, 0, 0, 0);
}
DEV i32x4 mfma_i8(i32x4 a, i32x4 b, i32x4 c){
  return __builtin_amdgcn_mfma_i32_16x16x64_i8(a, b, c, 0, 0, 0);
}

// async global->LDS, 16B per lane; lds dest = wave-uniform base + lane*16B
#define GLOAD_LDS16(gptr, ldsptr) \
  __builtin_amdgcn_global_load_lds( \
      (const __attribute__((address_space(1))) unsigned int*)(gptr), \
      (__attribute__((address_space(3))) unsigned int*)(ldsptr), 16, 0, 0)

// ---------------- weight sign-quantization (int8) + |w| partial sums ----------------
__global__ __launch_bounds__(256) void k_quant_w(
    const float* __restrict__ wq, const float* __restrict__ wg, const float* __restrict__ wp,
    signed char* __restrict__ oq, signed char* __restrict__ og, signed char* __restrict__ op,
    float* __restrict__ partials)
{
  int blk = blockIdx.x, t = threadIdx.x;
  const float* src; signed char* dst; long base;
  if (blk < 3072){ src=wq; dst=oq; base=(long)blk*4096; }
  else if (blk < 4096){ src=wg; dst=og; base=(long)(blk-3072)*4096; }
  else { src=wp; dst=op; base=(long)(blk-4096)*4096; }
  float s = 0.f;
  #pragma unroll
  for (int i=0;i<4;i++){
    long e = base + (long)(i*256 + t)*4;
    float4 v = *reinterpret_cast<const float4*>(src + e);
    s += fabsf(v.x)+fabsf(v.y)+fabsf(v.z)+fabsf(v.w);
    signed char tmp[4];
    tmp[0] = (v.x>0.f)?1:((v.x<0.f)?-1:0);
    tmp[1] = (v.y>0.f)?1:((v.y<0.f)?-1:0);
    tmp[2] = (v.z>0.f)?1:((v.z<0.f)?-1:0);
    tmp[3] = (v.w>0.f)?1:((v.w<0.f)?-1:0);
    *reinterpret_cast<unsigned int*>(dst + e) = *reinterpret_cast<unsigned int*>(tmp);
  }
  #pragma unroll
  for (int m=1;m<64;m<<=1) s += __shfl_xor(s, m);
  __shared__ float red[4];
  if ((t&63)==0) red[t>>6]=s;
  __syncthreads();
  if (t==0) partials[blk] = red[0]+red[1]+red[2]+red[3];
}

__global__ void k_finalize(const float* __restrict__ partials, float* __restrict__ scales)
{
  int t = threadIdx.x;
  __shared__ float red[4];
  for (int w=0; w<3; w++){
    int s0 = (w==0)?0:((w==1)?3072:4096);
    int s1 = (w==0)?3072:((w==1)?4096:5120);
    float acc = 0.f;
    for (int i=s0+t; i<s1; i+=256) acc += partials[i];
    #pragma unroll
    for (int m=1;m<64;m<<=1) acc += __shfl_xor(acc, m);
    if ((t&63)==0) red[t>>6]=acc;
    __syncthreads();
    if (t==0){
      float total = red[0]+red[1]+red[2]+red[3];
      float denom = (w==0)? 12582912.0f : 4194304.0f;
      float wsc = fmaxf(total/denom, 1e-5f);
      scales[w] = wsc / 127.0f;           // folded w_scale/127
    }
    __syncthreads();
  }
}

// ---------------- activation quantization -> int8 ----------------
__global__ __launch_bounds__(256) void k_quant_x(const float* __restrict__ x,
    signed char* __restrict__ xq, float* __restrict__ xs)
{
  int row=blockIdx.x, t=threadIdx.x;
  const float* xr = x + (long)row*2048;
  float v[8];
  float4 a = *reinterpret_cast<const float4*>(xr + t*8);
  float4 b = *reinterpret_cast<const float4*>(xr + t*8 + 4);
  v[0]=a.x; v[1]=a.y; v[2]=a.z; v[3]=a.w; v[4]=b.x; v[5]=b.y; v[6]=b.z; v[7]=b.w;
  float mx=0.f;
  #pragma unroll
  for (int j=0;j<8;j++) mx = fmaxf(mx, fabsf(v[j]));
  #pragma unroll
  for (int m=1;m<64;m<<=1) mx = fmaxf(mx, __shfl_xor(mx, m));
  __shared__ float red[4];
  if ((t&63)==0) red[t>>6]=mx;
  __syncthreads();
  float sc = fmaxf(fmaxf(fmaxf(red[0],red[1]),fmaxf(red[2],red[3])), 1e-5f);
  if (t==0) xs[row]=sc;
  signed char q[8];
  #pragma unroll
  for (int j=0;j<8;j++) q[j] = (signed char)(int)rintf((v[j]/sc)*127.f);
  *reinterpret_cast<uint2*>(xq + (long)row*2048 + t*8) = *reinterpret_cast<uint2*>(q);
}

// ---------------- bitlinear GEMM, i8 MFMA, 128x128 tile, BK=64, 3-buffer distance-2 pipeline ----------------
// iter t: stage tile t+2 (4 gloads/wave), vmcnt(8) [forces tile t], barrier,
// 8 ds_read_b128 + 16 MFMA, trailing barrier. Both-sides granule-XOR swizzle (BK=64 variant).
// XCD-chunked + 8x8 super-tile swizzle.
// MODE 0: merged qkv+gate (bn<48 qkv, else gate/decay); MODE 2: proj -> f32
template<int MODE, int NBN>
__global__ __launch_bounds__(256, 3) void k_gemm(
    const signed char* __restrict__ A, const signed char* __restrict__ Bw,
    const float* __restrict__ xs, const float* __restrict__ scales,
    const float* __restrict__ bias0, const float* __restrict__ bias1,
    unsigned short* __restrict__ oq, unsigned short* __restrict__ ok, unsigned short* __restrict__ ov,
    float* __restrict__ decay, float* __restrict__ of32)
{
  __shared__ signed char As[3][128*64];
  __shared__ signed char Bs[3][128*64];
  const int K = 2048, NT = 32;          // K-tiles of 64
  int tid=threadIdx.x;
  // block swizzle: XCD-contiguous chunks, then 8x8 (bn,bm) super-tiles
  const int nwg = NBN*64, cpx = nwg>>3;
  int wg  = ((int)blockIdx.x & 7)*cpx + ((int)blockIdx.x >> 3);
  int super = wg >> 6, inner = wg & 63;
  int bn = (super % (NBN>>3))*8 + (inner & 7);
  int bm = (super / (NBN>>3))*8 + (inner >> 3);
  long n0=(long)bn*128, m0=(long)bm*128;
  int wave=tid>>6, lane=tid&63, l15=lane&15, l4=lane>>4;
  int wr=wave>>1, wc=wave&1;
  // BK=64 staging: each gload = 1KB = 16 rows x 64B; lane -> row lane>>2, granule lane&3
  int srow = wave*32 + (lane>>2);                 // row within 128 (two gloads: +0, +16)
  int scol = ((lane&3) ^ ((lane>>2)&3))*16;       // pre-swizzled source col (bytes)
  i32x4 z4 = {0,0,0,0};
  i32x4 acc[4][4];
  #pragma unroll
  for (int i=0;i<4;i++)
    #pragma unroll
    for (int j=0;j<4;j++) acc[i][j]=z4;

#define STAGE_ALL(buf, kt) do{ \
    GLOAD_LDS16(A  + (m0 + srow +  0)*K + (kt) + scol, &As[buf][(wave*32 +  0)*64]); \
    GLOAD_LDS16(A  + (m0 + srow + 16)*K + (kt) + scol, &As[buf][(wave*32 + 16)*64]); \
    GLOAD_LDS16(Bw + (n0 + srow +  0)*K + (kt) + scol, &Bs[buf][(wave*32 +  0)*64]); \
    GLOAD_LDS16(Bw + (n0 + srow + 16)*K + (kt) + scol, &Bs[buf][(wave*32 + 16)*64]); }while(0)
// fragment: row base multiple of 16 -> (row&3)==(l15&3); granule = l4 ^ (l15&3)
#define RD_A(buf, mr) (*reinterpret_cast<const i32x4*>(&As[buf][(wr*64+(mr)*16+l15)*64 + ((l4 ^ (l15&3))<<4)]))
#define RD_B(buf, nr) (*reinterpret_cast<const i32x4*>(&Bs[buf][(wc*64+(nr)*16+l15)*64 + ((l4 ^ (l15&3))<<4)]))

  // prologue: stage tiles 0,1 -> bufs 0,1
  STAGE_ALL(0, 0);
  STAGE_ALL(1, 64);

  int c = 0;
  for (int t=0; t<NT; ++t){
    if (t+2 < NT){
      int cn = c+2; if (cn>=3) cn-=3;
      STAGE_ALL(cn, (t+2)*64);
      asm volatile("s_waitcnt vmcnt(8)" ::: "memory");  // tile t landed; t+1,t+2 in flight
    } else if (t+1 < NT){
      asm volatile("s_waitcnt vmcnt(4)" ::: "memory");  // tile t landed; t+1 in flight
    } else {
      asm volatile("s_waitcnt vmcnt(0)" ::: "memory");
    }
    __builtin_amdgcn_s_barrier();
    __builtin_amdgcn_s_setprio(1);
    {
      i32x4 af[4], bfr[4];
      #pragma unroll
      for (int mr=0;mr<4;mr++) af[mr] = RD_A(c,mr);
      #pragma unroll
      for (int nr=0;nr<4;nr++) bfr[nr] = RD_B(c,nr);
      #pragma unroll
      for (int mr=0;mr<4;mr++)
        #pragma unroll
        for (int nr=0;nr<4;nr++)
          acc[mr][nr] = mfma_i8(af[mr], bfr[nr], acc[mr][nr]);
    }
    __builtin_amdgcn_s_setprio(0);
    if (t+1 < NT) __builtin_amdgcn_s_barrier();   // buf c's reads done -> reusable
    c = (c+1==3)?0:c+1;
  }

  if (MODE==0 && bn < 48){
    float fac = scales[0];
    float xsv[4][4];
    #pragma unroll
    for (int mr=0;mr<4;mr++)
      #pragma unroll
      for (int r2=0;r2<4;r2++)
        xsv[mr][r2] = xs[m0 + wr*64 + mr*16 + 4*l4 + r2] * fac;
    int sidx = (int)(n0 >> 11);
    unsigned short* dst = (sidx==0)?oq:((sidx==1)?ok:ov);
    int c0 = (int)(n0 & 2047);
    #pragma unroll
    for (int nr=0;nr<4;nr++){
      int cc = c0 + wc*64 + nr*16 + l15;
      float bv = bias0[n0 + wc*64 + nr*16 + l15];
      #pragma unroll
      for (int mr=0;mr<4;mr++)
        #pragma unroll
        for (int r2=0;r2<4;r2++){
          long grow = m0 + wr*64 + mr*16 + 4*l4 + r2;
          dst[grow*2048 + cc] = f2bf((float)acc[mr][nr][r2]*xsv[mr][r2] + bv);
        }
    }
  } else if (MODE==0){
    // gate branch: bn in [48,64)
    int bng = bn - 48;
    float fac = scales[1];
    float xsv[4][4];
    #pragma unroll
    for (int mr=0;mr<4;mr++)
      #pragma unroll
      for (int r2=0;r2<4;r2++)
        xsv[mr][r2] = xs[m0 + wr*64 + mr*16 + 4*l4 + r2] * fac;
    float* red = reinterpret_cast<float*>(As);  // buf0 scratch; last tile read buf (NT-1)%3=1
    #pragma unroll
    for (int nr=0;nr<4;nr++){
      float bv = bias1[bng*128 + wc*64 + nr*16 + l15];
      float ssum = 0.f;
      #pragma unroll
      for (int mr=0;mr<4;mr++)
        #pragma unroll
        for (int r2=0;r2<4;r2++){
          float val = (float)acc[mr][nr][r2]*xsv[mr][r2] + bv;
          ssum += 1.f/(1.f + expf(-val));
        }
      ssum += __shfl_xor(ssum, 16);
      ssum += __shfl_xor(ssum, 32);
      if (l4==0) red[wr*128 + wc*64 + nr*16 + l15] = ssum;
    }
    __syncthreads();
    if (tid < 128){
      float d = (red[tid] + red[128+tid]) * (1.0f/128.0f);
      decay[((long)bm*16 + bng)*128 + tid] = d;
    }
  } else {
    float fac = scales[2];
    float xsv[4][4];
    #pragma unroll
    for (int mr=0;mr<4;mr++)
      #pragma unroll
      for (int r2=0;r2<4;r2++)
        xsv[mr][r2] = xs[m0 + wr*64 + mr*16 + 4*l4 + r2] * fac;
    #pragma unroll
    for (int nr=0;nr<4;nr++){
      long cc = n0 + wc*64 + nr*16 + l15;
      float bv = bias0[cc];
      #pragma unroll
      for (int mr=0;mr<4;mr++)
        #pragma unroll
        for (int r2=0;r2<4;r2++){
          long grow = m0 + wr*64 + mr*16 + 4*l4 + r2;
          of32[grow*2048 + cc] = (float)acc[mr][nr][r2]*xsv[mr][r2] + bv;
        }
    }
  }
#undef STAGE_ALL
#undef RD_A
#undef RD_B
}

// ---------------- Phase A: per-token 16x16 HEAD-mixing attention ----------------
__global__ __launch_bounds__(256) void k_attnA(const unsigned short* __restrict__ qb,
    const unsigned short* __restrict__ kb, const unsigned short* __restrict__ vb,
    unsigned short* __restrict__ aof)
{
  __shared__ unsigned short at[4][16*32];    // attn, zero-padded g in [16,32)
  __shared__ unsigned short vT[4][128*40];   // v^T [e][g], row stride 40, zero-padded
  int tid=threadIdx.x, wave=tid>>6, lane=tid&63, l15=lane&15, l4=lane>>4;
  const float SCALE = 0.08838834764831845f;

  for (int i=lane;i<16*32;i+=64) at[wave][i]=0;
  for (int i=lane;i<128*40;i+=64) vT[wave][i]=0;

  long token = (long)blockIdx.x*4 + wave;
  long base = token*2048;

  bf16x8 qf[4], kf[4];
  #pragma unroll
  for (int kk=0;kk<4;kk++){
    qf[kk] = *reinterpret_cast<const bf16x8*>(qb + base + l15*128 + kk*32 + l4*8);
    kf[kk] = *reinterpret_cast<const bf16x8*>(kb + base + l15*128 + kk*32 + l4*8);
  }
  {
    int g = lane>>2, e0 = (lane&3)*32;
    #pragma unroll
    for (int j=0;j<4;j++){
      u32x4 vv = *reinterpret_cast<const u32x4*>(vb + base + g*128 + e0 + j*8);
      unsigned short tmp[8];
      *reinterpret_cast<u32x4*>(tmp) = vv;
      #pragma unroll
      for (int t2=0;t2<8;t2++) vT[wave][(e0+j*8+t2)*40 + g] = tmp[t2];
    }
  }

  f32x4 s = {0.f,0.f,0.f,0.f};
  #pragma unroll
  for (int kk=0;kk<4;kk++) s = mfma16(qf[kk], kf[kk], s);

  #pragma unroll
  for (int r2=0;r2<4;r2++){
    float v = s[r2];
    float m = v;
    m = fmaxf(m, __shfl_xor(m,1)); m = fmaxf(m, __shfl_xor(m,2));
    m = fmaxf(m, __shfl_xor(m,4)); m = fmaxf(m, __shfl_xor(m,8));
    float p = expf((v-m)*SCALE);
    float sum = p;
    sum += __shfl_xor(sum,1); sum += __shfl_xor(sum,2);
    sum += __shfl_xor(sum,4); sum += __shfl_xor(sum,8);
    at[wave][(4*l4+r2)*32 + l15] = f2bf(p/sum);
  }
  __syncthreads();

  bf16x8 pa = *reinterpret_cast<const bf16x8*>(&at[wave][l15*32 + l4*8]);
  #pragma unroll
  for (int eb=0;eb<8;eb++){
    bf16x8 vf = *reinterpret_cast<const bf16x8*>(&vT[wave][(eb*16+l15)*40 + l4*8]);
    f32x4 z4 = {0.f,0.f,0.f,0.f};
    f32x4 o = mfma16(pa, vf, z4);
    #pragma unroll
    for (int r2=0;r2<4;r2++)
      aof[base + (long)(4*l4+r2)*128 + eb*16 + l15] = f2bf(o[r2]);
  }
}

// ---------------- Phase B1: per-chunk kv-update upd[e][d] = v^T . k ----------------
__global__ __launch_bounds__(256) void k_updB1(
    const unsigned short* __restrict__ kb, const unsigned short* __restrict__ vb,
    float* __restrict__ upds)
{
  __shared__ unsigned short kT[128*128];
  __shared__ unsigned short vT[128*128];
  int bid=blockIdx.x;
  int ch = bid&31, h=(bid>>5)&15, b=bid>>9;
  int tid=threadIdx.x, wave=tid>>6, lane=tid&63, l15=lane&15, l4=lane>>4;
  long base = ((long)b*4096 + (long)ch*128)*2048 + h*128;

  #pragma unroll
  for (int i=0;i<8;i++){
    int s = tid + i*256;
    int l = s>>4, sl = s&15;
    unsigned short tmp[8];
    u32x4 v1 = *reinterpret_cast<const u32x4*>(kb + base + (long)l*2048 + sl*8);
    *reinterpret_cast<u32x4*>(tmp) = v1;
    #pragma unroll
    for (int j=0;j<8;j++){
      int d = sl*8+j;
      kT[d*128 + (((l>>3)^(d&15))<<3) + (l&7)] = tmp[j];
    }
    u32x4 v2 = *reinterpret_cast<const u32x4*>(vb + base + (long)l*2048 + sl*8);
    *reinterpret_cast<u32x4*>(tmp) = v2;
    #pragma unroll
    for (int j=0;j<8;j++){
      int e = sl*8+j;
      vT[e*128 + (((l>>3)^(e&15))<<3) + (l&7)] = tmp[j];
    }
  }
  __syncthreads();

  f32x4 z4 = {0.f,0.f,0.f,0.f};
  f32x4 acc[2][8];
  #pragma unroll
  for (int er=0;er<2;er++)
    #pragma unroll
    for (int dc=0;dc<8;dc++) acc[er][dc]=z4;

  #pragma unroll
  for (int kk=0;kk<4;kk++){
    bf16x8 xf[2];
    #pragma unroll
    for (int er=0;er<2;er++){
      int e = wave*32 + er*16 + l15;
      xf[er] = *reinterpret_cast<const bf16x8*>(vT + e*128 + (((kk*4+l4)^(e&15))<<3));
    }
    #pragma unroll
    for (int dc=0;dc<8;dc++){
      int d = dc*16 + l15;
      bf16x8 kf = *reinterpret_cast<const bf16x8*>(kT + d*128 + (((kk*4+l4)^(d&15))<<3));
      #pragma unroll
      for (int er=0;er<2;er++)
        acc[er][dc] = mfma16(xf[er], kf, acc[er][dc]);
    }
  }

  float* dst = upds + (long)bid*16384;
  #pragma unroll
  for (int er=0;er<2;er++)
    #pragma unroll
    for (int dc=0;dc<8;dc++)
      #pragma unroll
      for (int r2=0;r2<4;r2++){
        int e = wave*32 + er*16 + 4*l4 + r2;
        int d = dc*16 + l15;
        dst[e*128 + d] = acc[er][dc][r2];
      }
}

// ---------------- Phase B2: in-place elementwise scan over chunks ----------------
__global__ __launch_bounds__(256) void k_scanB2(float* __restrict__ buf,
    const float* __restrict__ decay)
{
  int bid=blockIdx.x;
  int strip = bid&7, bh = bid>>3;
  int b = bh>>4, h = bh&15;
  int t = threadIdx.x;
  int f0 = t, f1 = t + 256;
  int e0 = strip*16 + (f0>>5), d0 = (f0&31)*4;
  int e1 = strip*16 + (f1>>5);
  long base = (long)bh * 32 * 16384;
  long o0 = (long)e0*128 + d0;
  long o1 = (long)e1*128 + d0;
  float4 s0 = {0.f,0.f,0.f,0.f}, s1 = {0.f,0.f,0.f,0.f};
  for (int ch=0; ch<32; ch++){
    float* p = buf + base + (long)ch*16384;
    float4 u0 = *reinterpret_cast<float4*>(p + o0);
    float4 u1 = *reinterpret_cast<float4*>(p + o1);
    *reinterpret_cast<float4*>(p + o0) = s0;
    *reinterpret_cast<float4*>(p + o1) = s1;
    float4 dc = *reinterpret_cast<const float4*>(decay + ((long)(b*32+ch)*16 + h)*128 + d0);
    s0.x = s0.x*dc.x + u0.x; s0.y = s0.y*dc.y + u0.y;
    s0.z = s0.z*dc.z + u0.z; s0.w = s0.w*dc.w + u0.w;
    s1.x = s1.x*dc.x + u1.x; s1.y = s1.y*dc.y + u1.y;
    s1.z = s1.z*dc.z + u1.z; s1.w = s1.w*dc.w + u1.w;
  }
}

// ---------------- Phase B3: recur[l][e] = q . state[e][:], hi/lo split, RMW aof ----------------
__global__ __launch_bounds__(256) void k_recurB3(
    const unsigned short* __restrict__ qb, const float* __restrict__ upds,
    unsigned short* __restrict__ aof)
{
  __shared__ unsigned short sh[128*128];
  __shared__ unsigned short slo[128*128];
  int bid=blockIdx.x;
  int ch = bid&31, h=(bid>>5)&15, b=bid>>9;
  int tid=threadIdx.x, wave=tid>>6, lane=tid&63, l15=lane&15, l4=lane>>4;
  long slab = (long)bid*16384;
  long base = ((long)b*4096 + (long)ch*128)*2048 + h*128;

  #pragma unroll
  for (int i=0;i<8;i++){
    int s = tid + i*256;
    int e = s>>4, sl = s&15;
    float4 a = *reinterpret_cast<const float4*>(upds + slab + (long)e*128 + sl*8);
    float4 c = *reinterpret_cast<const float4*>(upds + slab + (long)e*128 + sl*8 + 4);
    float vv[8] = {a.x,a.y,a.z,a.w,c.x,c.y,c.z,c.w};
    unsigned short hi[8], lo[8];
    #pragma unroll
    for (int j=0;j<8;j++){
      hi[j] = f2bf(vv[j]);
      lo[j] = f2bf(vv[j] - bf2f(hi[j]));
    }
    int slot = e*128 + ((sl ^ (e&15))<<3);
    *reinterpret_cast<u32x4*>(sh + slot)  = *reinterpret_cast<u32x4*>(hi);
    *reinterpret_cast<u32x4*>(slo + slot) = *reinterpret_cast<u32x4*>(lo);
  }

  bf16x8 qf[2][4];
  #pragma unroll
  for (int mr=0;mr<2;mr++)
    #pragma unroll
    for (int kk=0;kk<4;kk++)
      qf[mr][kk] = *reinterpret_cast<const bf16x8*>(qb + base + (long)(wave*32+mr*16+l15)*2048 + kk*32 + l4*8);
  __syncthreads();

  f32x4 z4 = {0.f,0.f,0.f,0.f};
  f32x4 acc[2][8];
  #pragma unroll
  for (int mr=0;mr<2;mr++)
    #pragma unroll
    for (int ec=0;ec<8;ec++) acc[mr][ec]=z4;

  #pragma unroll
  for (int kk=0;kk<4;kk++)
    #pragma unroll
    for (int ec=0;ec<8;ec++){
      int e = ec*16 + l15;
      int slot = (((kk*4+l4)^(e&15))<<3);
      bf16x8 tfh = *reinterpret_cast<const bf16x8*>(sh + e*128 + slot);
      bf16x8 tfl = *reinterpret_cast<const bf16x8*>(slo + e*128 + slot);
      #pragma unroll
      for (int mr=0;mr<2;mr++){
        acc[mr][ec] = mfma16(qf[mr][kk], tfh, acc[mr][ec]);
        acc[mr][ec] = mfma16(qf[mr][kk], tfl, acc[mr][ec]);
      }
    }

  #pragma unroll
  for (int mr=0;mr<2;mr++)
    #pragma unroll
    for (int ec=0;ec<8;ec++)
      #pragma unroll
      for (int r2=0;r2<4;r2++){
        long o = base + (long)(wave*32+mr*16+4*l4+r2)*2048 + ec*16 + l15;
        aof[o] = f2bf(bf2f(aof[o]) + acc[mr][ec][r2]);
      }
}

// ---------------- rmsnorm (bf16 in) + re-quantize -> int8 ----------------
__global__ __launch_bounds__(256) void k_rmsnorm_quant(const unsigned short* __restrict__ ain,
    const float* __restrict__ normw, signed char* __restrict__ x2q, float* __restrict__ xs2)
{
  int row=blockIdx.x, t=threadIdx.x;
  const unsigned short* rp = ain + (long)row*2048;
  u32x4 raw = *reinterpret_cast<const u32x4*>(rp + t*8);
  unsigned short tmp[8];
  *reinterpret_cast<u32x4*>(tmp) = raw;
  float xv[8]; float ss=0.f;
  #pragma unroll
  for (int j=0;j<8;j++){ xv[j]=bf2f(tmp[j]); ss += xv[j]*xv[j]; }
  #pragma unroll
  for (int m=1;m<64;m<<=1) ss += __shfl_xor(ss, m);
  __shared__ float red[4];
  if ((t&63)==0) red[t>>6]=ss;
  __syncthreads();
  float ms = (red[0]+red[1]+red[2]+red[3])*(1.0f/2048.0f) + 1e-6f;
  float rs = 1.0f/sqrtf(ms);
  __syncthreads();
  float4 w0 = *reinterpret_cast<const float4*>(normw + t*8);
  float4 w1 = *reinterpret_cast<const float4*>(normw + t*8 + 4);
  float wv[8] = {w0.x,w0.y,w0.z,w0.w,w1.x,w1.y,w1.z,w1.w};
  float y[8]; float mx=0.f;
  #pragma unroll
  for (int j=0;j<8;j++){ y[j] = xv[j]*rs*wv[j]; mx = fmaxf(mx, fabsf(y[j])); }
  #pragma unroll
  for (int m=1;m<64;m<<=1) mx = fmaxf(mx, __shfl_xor(mx, m));
  __shared__ float red2[4];
  if ((t&63)==0) red2[t>>6]=mx;
  __syncthreads();
  float sc = fmaxf(fmaxf(fmaxf(red2[0],red2[1]),fmaxf(red2[2],red2[3])), 1e-5f);
  if (t==0) xs2[row]=sc;
  signed char q[8];
  #pragma unroll
  for (int j=0;j<8;j++) q[j] = (signed char)(int)rintf((y[j]/sc)*127.f);
  *reinterpret_cast<uint2*>(x2q + (long)row*2048 + t*8) = *reinterpret_cast<uint2*>(q);
}

// ---------------- host launch ----------------
extern "C" void kernel_launch(void* const* d_in, const int* in_sizes, int n_in,
                              void* d_out, int out_size, void* d_ws, size_t ws_size,
                              hipStream_t stream)
{
  const float* x      = (const float*)d_in[0];
  const float* qkv_w  = (const float*)d_in[1];
  const float* qkv_b  = (const float*)d_in[2];
  const float* gate_w = (const float*)d_in[3];
  const float* gate_b = (const float*)d_in[4];
  const float* proj_w = (const float*)d_in[5];
  const float* proj_b = (const float*)d_in[6];
  const float* norm_w = (const float*)d_in[7];
  (void)in_sizes; (void)n_in; (void)out_size; (void)ws_size;

  char* ws = (char*)d_ws;
  const size_t MB = 1024UL*1024UL;
  // wq_qkv and wq_gate CONTIGUOUS (merged GEMM reads rows 0..8191)
  signed char* wq_proj = (signed char*)(ws + 0*MB);   // 4MB, alive to end
  signed char* wq_qkv  = (signed char*)(ws + 4*MB);   // 12MB (rows 0..6143)
  signed char* wq_gate = (signed char*)(ws + 16*MB);  // 4MB  (rows 6144..8191)
  signed char* xq      = (signed char*)(ws + 20*MB);  // 16MB, dies after merged gemm
  float*       upds    = (float*)(ws + 4*MB);         // 64MB f32 (1024 slabs), aliases wq_qkv/gate/xq
  unsigned short* qb   = (unsigned short*)(ws + 68*MB);   // 32MB (x2q aliases after B3)
  unsigned short* kb   = (unsigned short*)(ws + 100*MB);  // 32MB
  unsigned short* vb   = (unsigned short*)(ws + 132*MB);  // 32MB
  unsigned short* aof  = (unsigned short*)(ws + 164*MB);  // 32MB bf16
  signed char* x2q     = (signed char*)qb;
  float* xs       = (float*)(ws + 196*MB);
  float* xs2      = xs + 8192;
  float* decay    = xs2 + 8192;
  float* partials = decay + 131072;
  float* scales   = partials + 5120;

  k_quant_w<<<5120,256,0,stream>>>(qkv_w, gate_w, proj_w, wq_qkv, wq_gate, wq_proj, partials);
  k_finalize<<<1,256,0,stream>>>(partials, scales);
  k_quant_x<<<8192,256,0,stream>>>(x, xq, xs);
  k_gemm<0,64><<<4096,256,0,stream>>>(xq, wq_qkv, xs, scales, qkv_b, gate_b,
      qb,kb,vb, decay, nullptr);
  k_attnA<<<2048,256,0,stream>>>(qb,kb,vb, aof);
  k_updB1<<<1024,256,0,stream>>>(kb, vb, upds);
  k_scanB2<<<256,256,0,stream>>>(upds, decay);
  k_recurB3<<<1024,256,0,stream>>>(qb, upds, aof);
  k_rmsnorm_quant<<<8192,256,0,stream>>>(aof, norm_w, x2q, xs2);
  k_gemm<2,16><<<1024,256,0,stream>>>(x2q, wq_proj, xs2, scales, proj_b, nullptr,
      nullptr,nullptr,nullptr, nullptr, (float*)d_out);
}

// Round 15
// 390.622 us; speedup vs baseline: 1.0352x; 1.0290x over previous
//
#include <hip/hip_runtime.h>
#include <stdint.h>

typedef __attribute__((ext_vector_type(4))) float f32x4;
typedef __attribute__((ext_vector_type(8))) __bf16 bf16x8;
typedef __attribute__((ext_vector_type(4))) unsigned int u32x4;
typedef __attribute__((ext_vector_type(4))) int i32x4;

#define DEV static __device__ __forceinline__

DEV float bf2f(unsigned short h){ union{unsigned int u; float f;} v; v.u=((unsigned int)h)<<16; return v.f; }
DEV unsigned short f2bf(float f){ union{float ff; unsigned int u;} v; v.ff=f; unsigned int u=v.u;
  u += 0x7fffu + ((u>>16)&1u); return (unsigned short)(u>>16); }

DEV f32x4 mfma16(bf16x8 a, bf16x8 b, f32x4 c){
  return __builtin_amdgcn_mfma_f32_16x16x32_bf16(a, b, c, 0, 0, 0);
}
DEV i32x4 mfma_i8(i32x4 a, i32x4 b, i32x4 c){
  return __builtin_amdgcn_mfma_i32_16x16x64_i8(a, b, c, 0, 0, 0);
}

// async global->LDS, 16B per lane; lds dest = wave-uniform base + lane*16B
#define GLOAD_LDS16(gptr, ldsptr) \
  __builtin_amdgcn_global_load_lds( \
      (const __attribute__((address_space(1))) unsigned int*)(gptr), \
      (__attribute__((address_space(3))) unsigned int*)(ldsptr), 16, 0, 0)

// ---------------- fused quantization: weights (blocks 0..5119) + activations (5120..13311) ----------------
__global__ __launch_bounds__(256) void k_quant_all(
    const float* __restrict__ wq, const float* __restrict__ wg, const float* __restrict__ wp,
    const float* __restrict__ x,
    signed char* __restrict__ oq, signed char* __restrict__ og, signed char* __restrict__ op,
    signed char* __restrict__ xq, float* __restrict__ xs,
    float* __restrict__ partials)
{
  int blk = blockIdx.x, t = threadIdx.x;
  if (blk < 5120){
    const float* src; signed char* dst; long base;
    if (blk < 3072){ src=wq; dst=oq; base=(long)blk*4096; }
    else if (blk < 4096){ src=wg; dst=og; base=(long)(blk-3072)*4096; }
    else { src=wp; dst=op; base=(long)(blk-4096)*4096; }
    float s = 0.f;
    #pragma unroll
    for (int i=0;i<4;i++){
      long e = base + (long)(i*256 + t)*4;
      float4 v = *reinterpret_cast<const float4*>(src + e);
      s += fabsf(v.x)+fabsf(v.y)+fabsf(v.z)+fabsf(v.w);
      signed char tmp[4];
      tmp[0] = (v.x>0.f)?1:((v.x<0.f)?-1:0);
      tmp[1] = (v.y>0.f)?1:((v.y<0.f)?-1:0);
      tmp[2] = (v.z>0.f)?1:((v.z<0.f)?-1:0);
      tmp[3] = (v.w>0.f)?1:((v.w<0.f)?-1:0);
      *reinterpret_cast<unsigned int*>(dst + e) = *reinterpret_cast<unsigned int*>(tmp);
    }
    #pragma unroll
    for (int m=1;m<64;m<<=1) s += __shfl_xor(s, m);
    __shared__ float red[4];
    if ((t&63)==0) red[t>>6]=s;
    __syncthreads();
    if (t==0) partials[blk] = red[0]+red[1]+red[2]+red[3];
  } else {
    int row = blk - 5120;
    const float* xr = x + (long)row*2048;
    float v[8];
    float4 a = *reinterpret_cast<const float4*>(xr + t*8);
    float4 b = *reinterpret_cast<const float4*>(xr + t*8 + 4);
    v[0]=a.x; v[1]=a.y; v[2]=a.z; v[3]=a.w; v[4]=b.x; v[5]=b.y; v[6]=b.z; v[7]=b.w;
    float mx=0.f;
    #pragma unroll
    for (int j=0;j<8;j++) mx = fmaxf(mx, fabsf(v[j]));
    #pragma unroll
    for (int m=1;m<64;m<<=1) mx = fmaxf(mx, __shfl_xor(mx, m));
    __shared__ float red2[4];
    if ((t&63)==0) red2[t>>6]=mx;
    __syncthreads();
    float sc = fmaxf(fmaxf(fmaxf(red2[0],red2[1]),fmaxf(red2[2],red2[3])), 1e-5f);
    if (t==0) xs[row]=sc;
    signed char q[8];
    #pragma unroll
    for (int j=0;j<8;j++) q[j] = (signed char)(int)rintf((v[j]/sc)*127.f);
    *reinterpret_cast<uint2*>(xq + (long)row*2048 + t*8) = *reinterpret_cast<uint2*>(q);
  }
}

__global__ void k_finalize(const float* __restrict__ partials, float* __restrict__ scales)
{
  int t = threadIdx.x;
  __shared__ float red[4];
  for (int w=0; w<3; w++){
    int s0 = (w==0)?0:((w==1)?3072:4096);
    int s1 = (w==0)?3072:((w==1)?4096:5120);
    float acc = 0.f;
    for (int i=s0+t; i<s1; i+=256) acc += partials[i];
    #pragma unroll
    for (int m=1;m<64;m<<=1) acc += __shfl_xor(acc, m);
    if ((t&63)==0) red[t>>6]=acc;
    __syncthreads();
    if (t==0){
      float total = red[0]+red[1]+red[2]+red[3];
      float denom = (w==0)? 12582912.0f : 4194304.0f;
      float wsc = fmaxf(total/denom, 1e-5f);
      scales[w] = wsc / 127.0f;           // folded w_scale/127
    }
    __syncthreads();
  }
}

// ---------------- bitlinear GEMM, int8 MFMA (exact), 128x128 tile, BK=128 ----------------
// round-12 measured-best: stage tile t+1 (8 gloads/wave), vmcnt(8), raw barrier,
// 32 i8-MFMA, trailing barrier. Both-sides granule-XOR swizzle.
// XCD-chunked + 8x8 super-tile swizzle for L2 (4MB working set = XCD L2).
// MODE 0: merged qkv+gate (bn<48 qkv, else gate/decay); MODE 2: proj -> f32
template<int MODE, int NBN>
__global__ __launch_bounds__(256) void k_gemm(
    const signed char* __restrict__ A, const signed char* __restrict__ Bw,
    const float* __restrict__ xs, const float* __restrict__ scales,
    const float* __restrict__ bias0, const float* __restrict__ bias1,
    unsigned short* __restrict__ oq, unsigned short* __restrict__ ok, unsigned short* __restrict__ ov,
    float* __restrict__ decay, float* __restrict__ of32)
{
  __shared__ signed char As[2][128*128];
  __shared__ signed char Bs[2][128*128];
  const int K = 2048, NT = 16;          // K-tiles of 128
  int tid=threadIdx.x;
  // block swizzle: XCD-contiguous chunks, then 8x8 (bn,bm) super-tiles
  const int nwg = NBN*64, cpx = nwg>>3;
  int wg  = ((int)blockIdx.x & 7)*cpx + ((int)blockIdx.x >> 3);
  int super = wg >> 6, inner = wg & 63;
  int bn = (super % (NBN>>3))*8 + (inner & 7);
  int bm = (super / (NBN>>3))*8 + (inner >> 3);
  long n0=(long)bn*128, m0=(long)bm*128;
  int wave=tid>>6, lane=tid&63, l15=lane&15, l4=lane>>4;
  int wr=wave>>1, wc=wave&1;
  int srow = wave*8 + (lane>>3);                  // staging row within 32-row group
  int scol = ((lane&7) ^ ((lane>>3)&7))*16;       // pre-swizzled source col (bytes)
  i32x4 z4 = {0,0,0,0};
  i32x4 acc[4][4];
  #pragma unroll
  for (int i=0;i<4;i++)
    #pragma unroll
    for (int j=0;j<4;j++) acc[i][j]=z4;

#define STAGE_ALL(buf, kt) do{ \
    GLOAD_LDS16(A  + (m0 +  0 + srow)*K + (kt) + scol, &As[buf][(  0 + wave*8)*128]); \
    GLOAD_LDS16(A  + (m0 + 32 + srow)*K + (kt) + scol, &As[buf][( 32 + wave*8)*128]); \
    GLOAD_LDS16(A  + (m0 + 64 + srow)*K + (kt) + scol, &As[buf][( 64 + wave*8)*128]); \
    GLOAD_LDS16(A  + (m0 + 96 + srow)*K + (kt) + scol, &As[buf][( 96 + wave*8)*128]); \
    GLOAD_LDS16(Bw + (n0 +  0 + srow)*K + (kt) + scol, &Bs[buf][(  0 + wave*8)*128]); \
    GLOAD_LDS16(Bw + (n0 + 32 + srow)*K + (kt) + scol, &Bs[buf][( 32 + wave*8)*128]); \
    GLOAD_LDS16(Bw + (n0 + 64 + srow)*K + (kt) + scol, &Bs[buf][( 64 + wave*8)*128]); \
    GLOAD_LDS16(Bw + (n0 + 96 + srow)*K + (kt) + scol, &Bs[buf][( 96 + wave*8)*128]); }while(0)
// fragment: row base multiple of 16 -> (row&7)==(l15&7); granule pos = G ^ (row&7)
#define RD_A(buf, mr, kk) (*reinterpret_cast<const i32x4*>(&As[buf][(wr*64+(mr)*16+l15)*128 + ((((kk)*4+l4) ^ (l15&7))<<4)]))
#define RD_B(buf, nr, kk) (*reinterpret_cast<const i32x4*>(&Bs[buf][(wc*64+(nr)*16+l15)*128 + ((((kk)*4+l4) ^ (l15&7))<<4)]))

  // prologue: stage tile 0 -> buf 0
  STAGE_ALL(0, 0);

  for (int t=0; t<NT; ++t){
    int c = t&1;
    if (t+1 < NT){
      STAGE_ALL(c^1, (t+1)*128);
      asm volatile("s_waitcnt vmcnt(8)" ::: "memory");  // tile t landed; t+1 in flight
    } else {
      asm volatile("s_waitcnt vmcnt(0)" ::: "memory");
    }
    __builtin_amdgcn_s_barrier();
    __builtin_amdgcn_s_setprio(1);
    #pragma unroll
    for (int kk=0;kk<2;kk++){
      i32x4 af[4], bfr[4];
      #pragma unroll
      for (int mr=0;mr<4;mr++) af[mr] = RD_A(c,mr,kk);
      #pragma unroll
      for (int nr=0;nr<4;nr++) bfr[nr] = RD_B(c,nr,kk);
      #pragma unroll
      for (int mr=0;mr<4;mr++)
        #pragma unroll
        for (int nr=0;nr<4;nr++)
          acc[mr][nr] = mfma_i8(af[mr], bfr[nr], acc[mr][nr]);
    }
    __builtin_amdgcn_s_setprio(0);
    if (t+1 < NT) __builtin_amdgcn_s_barrier();   // buf c free for next stage
  }

  if (MODE==0 && bn < 48){
    float fac = scales[0];
    float xsv[4][4];
    #pragma unroll
    for (int mr=0;mr<4;mr++)
      #pragma unroll
      for (int r2=0;r2<4;r2++)
        xsv[mr][r2] = xs[m0 + wr*64 + mr*16 + 4*l4 + r2] * fac;
    int sidx = (int)(n0 >> 11);
    unsigned short* dst = (sidx==0)?oq:((sidx==1)?ok:ov);
    int c0 = (int)(n0 & 2047);
    #pragma unroll
    for (int nr=0;nr<4;nr++){
      int c = c0 + wc*64 + nr*16 + l15;
      float bv = bias0[n0 + wc*64 + nr*16 + l15];
      #pragma unroll
      for (int mr=0;mr<4;mr++)
        #pragma unroll
        for (int r2=0;r2<4;r2++){
          long grow = m0 + wr*64 + mr*16 + 4*l4 + r2;
          dst[grow*2048 + c] = f2bf((float)acc[mr][nr][r2]*xsv[mr][r2] + bv);
        }
    }
  } else if (MODE==0){
    // gate branch: bn in [48,64)
    int bng = bn - 48;
    float fac = scales[1];
    float xsv[4][4];
    #pragma unroll
    for (int mr=0;mr<4;mr++)
      #pragma unroll
      for (int r2=0;r2<4;r2++)
        xsv[mr][r2] = xs[m0 + wr*64 + mr*16 + 4*l4 + r2] * fac;
    float* red = reinterpret_cast<float*>(As);  // buf0 region; final reads were buf1 -> safe
    #pragma unroll
    for (int nr=0;nr<4;nr++){
      float bv = bias1[bng*128 + wc*64 + nr*16 + l15];
      float ssum = 0.f;
      #pragma unroll
      for (int mr=0;mr<4;mr++)
        #pragma unroll
        for (int r2=0;r2<4;r2++){
          float val = (float)acc[mr][nr][r2]*xsv[mr][r2] + bv;
          ssum += 1.f/(1.f + expf(-val));
        }
      ssum += __shfl_xor(ssum, 16);
      ssum += __shfl_xor(ssum, 32);
      if (l4==0) red[wr*128 + wc*64 + nr*16 + l15] = ssum;
    }
    __syncthreads();
    if (tid < 128){
      float d = (red[tid] + red[128+tid]) * (1.0f/128.0f);
      decay[((long)bm*16 + bng)*128 + tid] = d;
    }
  } else {
    float fac = scales[2];
    float xsv[4][4];
    #pragma unroll
    for (int mr=0;mr<4;mr++)
      #pragma unroll
      for (int r2=0;r2<4;r2++)
        xsv[mr][r2] = xs[m0 + wr*64 + mr*16 + 4*l4 + r2] * fac;
    #pragma unroll
    for (int nr=0;nr<4;nr++){
      long c = n0 + wc*64 + nr*16 + l15;
      float bv = bias0[c];
      #pragma unroll
      for (int mr=0;mr<4;mr++)
        #pragma unroll
        for (int r2=0;r2<4;r2++){
          long grow = m0 + wr*64 + mr*16 + 4*l4 + r2;
          of32[grow*2048 + c] = (float)acc[mr][nr][r2]*xsv[mr][r2] + bv;
        }
    }
  }
#undef STAGE_ALL
#undef RD_A
#undef RD_B
}

// ---------------- Phase A: per-token 16x16 HEAD-mixing attention ----------------
__global__ __launch_bounds__(256) void k_attnA(const unsigned short* __restrict__ qb,
    const unsigned short* __restrict__ kb, const unsigned short* __restrict__ vb,
    unsigned short* __restrict__ aof)
{
  __shared__ unsigned short at[4][16*32];    // attn, zero-padded g in [16,32)
  __shared__ unsigned short vT[4][128*40];   // v^T [e][g], row stride 40, zero-padded
  int tid=threadIdx.x, wave=tid>>6, lane=tid&63, l15=lane&15, l4=lane>>4;
  const float SCALE = 0.08838834764831845f;

  for (int i=lane;i<16*32;i+=64) at[wave][i]=0;
  for (int i=lane;i<128*40;i+=64) vT[wave][i]=0;

  long token = (long)blockIdx.x*4 + wave;
  long base = token*2048;

  bf16x8 qf[4], kf[4];
  #pragma unroll
  for (int kk=0;kk<4;kk++){
    qf[kk] = *reinterpret_cast<const bf16x8*>(qb + base + l15*128 + kk*32 + l4*8);
    kf[kk] = *reinterpret_cast<const bf16x8*>(kb + base + l15*128 + kk*32 + l4*8);
  }
  {
    int g = lane>>2, e0 = (lane&3)*32;
    #pragma unroll
    for (int j=0;j<4;j++){
      u32x4 vv = *reinterpret_cast<const u32x4*>(vb + base + g*128 + e0 + j*8);
      unsigned short tmp[8];
      *reinterpret_cast<u32x4*>(tmp) = vv;
      #pragma unroll
      for (int t2=0;t2<8;t2++) vT[wave][(e0+j*8+t2)*40 + g] = tmp[t2];
    }
  }

  f32x4 s = {0.f,0.f,0.f,0.f};
  #pragma unroll
  for (int kk=0;kk<4;kk++) s = mfma16(qf[kk], kf[kk], s);

  #pragma unroll
  for (int r2=0;r2<4;r2++){
    float v = s[r2];
    float m = v;
    m = fmaxf(m, __shfl_xor(m,1)); m = fmaxf(m, __shfl_xor(m,2));
    m = fmaxf(m, __shfl_xor(m,4)); m = fmaxf(m, __shfl_xor(m,8));
    float p = expf((v-m)*SCALE);
    float sum = p;
    sum += __shfl_xor(sum,1); sum += __shfl_xor(sum,2);
    sum += __shfl_xor(sum,4); sum += __shfl_xor(sum,8);
    at[wave][(4*l4+r2)*32 + l15] = f2bf(p/sum);
  }
  __syncthreads();

  bf16x8 pa = *reinterpret_cast<const bf16x8*>(&at[wave][l15*32 + l4*8]);
  #pragma unroll
  for (int eb=0;eb<8;eb++){
    bf16x8 vf = *reinterpret_cast<const bf16x8*>(&vT[wave][(eb*16+l15)*40 + l4*8]);
    f32x4 z4 = {0.f,0.f,0.f,0.f};
    f32x4 o = mfma16(pa, vf, z4);
    #pragma unroll
    for (int r2=0;r2<4;r2++)
      aof[base + (long)(4*l4+r2)*128 + eb*16 + l15] = f2bf(o[r2]);
  }
}

// ---------------- Phase B1: per-chunk kv-update upd[e][d] = v^T . k ----------------
__global__ __launch_bounds__(256) void k_updB1(
    const unsigned short* __restrict__ kb, const unsigned short* __restrict__ vb,
    float* __restrict__ upds)
{
  __shared__ unsigned short kT[128*128];
  __shared__ unsigned short vT[128*128];
  int bid=blockIdx.x;
  int ch = bid&31, h=(bid>>5)&15, b=bid>>9;
  int tid=threadIdx.x, wave=tid>>6, lane=tid&63, l15=lane&15, l4=lane>>4;
  long base = ((long)b*4096 + (long)ch*128)*2048 + h*128;

  #pragma unroll
  for (int i=0;i<8;i++){
    int s = tid + i*256;
    int l = s>>4, sl = s&15;
    unsigned short tmp[8];
    u32x4 v1 = *reinterpret_cast<const u32x4*>(kb + base + (long)l*2048 + sl*8);
    *reinterpret_cast<u32x4*>(tmp) = v1;
    #pragma unroll
    for (int j=0;j<8;j++){
      int d = sl*8+j;
      kT[d*128 + (((l>>3)^(d&15))<<3) + (l&7)] = tmp[j];
    }
    u32x4 v2 = *reinterpret_cast<const u32x4*>(vb + base + (long)l*2048 + sl*8);
    *reinterpret_cast<u32x4*>(tmp) = v2;
    #pragma unroll
    for (int j=0;j<8;j++){
      int e = sl*8+j;
      vT[e*128 + (((l>>3)^(e&15))<<3) + (l&7)] = tmp[j];
    }
  }
  __syncthreads();

  f32x4 z4 = {0.f,0.f,0.f,0.f};
  f32x4 acc[2][8];
  #pragma unroll
  for (int er=0;er<2;er++)
    #pragma unroll
    for (int dc=0;dc<8;dc++) acc[er][dc]=z4;

  #pragma unroll
  for (int kk=0;kk<4;kk++){
    bf16x8 xf[2];
    #pragma unroll
    for (int er=0;er<2;er++){
      int e = wave*32 + er*16 + l15;
      xf[er] = *reinterpret_cast<const bf16x8*>(vT + e*128 + (((kk*4+l4)^(e&15))<<3));
    }
    #pragma unroll
    for (int dc=0;dc<8;dc++){
      int d = dc*16 + l15;
      bf16x8 kf = *reinterpret_cast<const bf16x8*>(kT + d*128 + (((kk*4+l4)^(d&15))<<3));
      #pragma unroll
      for (int er=0;er<2;er++)
        acc[er][dc] = mfma16(xf[er], kf, acc[er][dc]);
    }
  }

  float* dst = upds + (long)bid*16384;
  #pragma unroll
  for (int er=0;er<2;er++)
    #pragma unroll
    for (int dc=0;dc<8;dc++)
      #pragma unroll
      for (int r2=0;r2<4;r2++){
        int e = wave*32 + er*16 + 4*l4 + r2;
        int d = dc*16 + l15;
        dst[e*128 + d] = acc[er][dc][r2];
      }
}

// ---------------- Phase B2: in-place elementwise scan over chunks ----------------
__global__ __launch_bounds__(256) void k_scanB2(float* __restrict__ buf,
    const float* __restrict__ decay)
{
  int bid=blockIdx.x;
  int strip = bid&7, bh = bid>>3;
  int b = bh>>4, h = bh&15;
  int t = threadIdx.x;
  int f0 = t, f1 = t + 256;
  int e0 = strip*16 + (f0>>5), d0 = (f0&31)*4;
  int e1 = strip*16 + (f1>>5);
  long base = (long)bh * 32 * 16384;
  long o0 = (long)e0*128 + d0;
  long o1 = (long)e1*128 + d0;
  float4 s0 = {0.f,0.f,0.f,0.f}, s1 = {0.f,0.f,0.f,0.f};
  for (int ch=0; ch<32; ch++){
    float* p = buf + base + (long)ch*16384;
    float4 u0 = *reinterpret_cast<float4*>(p + o0);
    float4 u1 = *reinterpret_cast<float4*>(p + o1);
    *reinterpret_cast<float4*>(p + o0) = s0;
    *reinterpret_cast<float4*>(p + o1) = s1;
    float4 dc = *reinterpret_cast<const float4*>(decay + ((long)(b*32+ch)*16 + h)*128 + d0);
    s0.x = s0.x*dc.x + u0.x; s0.y = s0.y*dc.y + u0.y;
    s0.z = s0.z*dc.z + u0.z; s0.w = s0.w*dc.w + u0.w;
    s1.x = s1.x*dc.x + u1.x; s1.y = s1.y*dc.y + u1.y;
    s1.z = s1.z*dc.z + u1.z; s1.w = s1.w*dc.w + u1.w;
  }
}

// ---------------- Phase B3: recur[l][e] = q . state[e][:], hi/lo split, RMW aof ----------------
__global__ __launch_bounds__(256) void k_recurB3(
    const unsigned short* __restrict__ qb, const float* __restrict__ upds,
    unsigned short* __restrict__ aof)
{
  __shared__ unsigned short sh[128*128];
  __shared__ unsigned short slo[128*128];
  int bid=blockIdx.x;
  int ch = bid&31, h=(bid>>5)&15, b=bid>>9;
  int tid=threadIdx.x, wave=tid>>6, lane=tid&63, l15=lane&15, l4=lane>>4;
  long slab = (long)bid*16384;
  long base = ((long)b*4096 + (long)ch*128)*2048 + h*128;

  #pragma unroll
  for (int i=0;i<8;i++){
    int s = tid + i*256;
    int e = s>>4, sl = s&15;
    float4 a = *reinterpret_cast<const float4*>(upds + slab + (long)e*128 + sl*8);
    float4 c = *reinterpret_cast<const float4*>(upds + slab + (long)e*128 + sl*8 + 4);
    float vv[8] = {a.x,a.y,a.z,a.w,c.x,c.y,c.z,c.w};
    unsigned short hi[8], lo[8];
    #pragma unroll
    for (int j=0;j<8;j++){
      hi[j] = f2bf(vv[j]);
      lo[j] = f2bf(vv[j] - bf2f(hi[j]));
    }
    int slot = e*128 + ((sl ^ (e&15))<<3);
    *reinterpret_cast<u32x4*>(sh + slot)  = *reinterpret_cast<u32x4*>(hi);
    *reinterpret_cast<u32x4*>(slo + slot) = *reinterpret_cast<u32x4*>(lo);
  }

  bf16x8 qf[2][4];
  #pragma unroll
  for (int mr=0;mr<2;mr++)
    #pragma unroll
    for (int kk=0;kk<4;kk++)
      qf[mr][kk] = *reinterpret_cast<const bf16x8*>(qb + base + (long)(wave*32+mr*16+l15)*2048 + kk*32 + l4*8);
  __syncthreads();

  f32x4 z4 = {0.f,0.f,0.f,0.f};
  f32x4 acc[2][8];
  #pragma unroll
  for (int mr=0;mr<2;mr++)
    #pragma unroll
    for (int ec=0;ec<8;ec++) acc[mr][ec]=z4;

  #pragma unroll
  for (int kk=0;kk<4;kk++)
    #pragma unroll
    for (int ec=0;ec<8;ec++){
      int e = ec*16 + l15;
      int slot = (((kk*4+l4)^(e&15))<<3);
      bf16x8 tfh = *reinterpret_cast<const bf16x8*>(sh + e*128 + slot);
      bf16x8 tfl = *reinterpret_cast<const bf16x8*>(slo + e*128 + slot);
      #pragma unroll
      for (int mr=0;mr<2;mr++){
        acc[mr][ec] = mfma16(qf[mr][kk], tfh, acc[mr][ec]);
        acc[mr][ec] = mfma16(qf[mr][kk], tfl, acc[mr][ec]);
      }
    }

  #pragma unroll
  for (int mr=0;mr<2;mr++)
    #pragma unroll
    for (int ec=0;ec<8;ec++)
      #pragma unroll
      for (int r2=0;r2<4;r2++){
        long o = base + (long)(wave*32+mr*16+4*l4+r2)*2048 + ec*16 + l15;
        aof[o] = f2bf(bf2f(aof[o]) + acc[mr][ec][r2]);
      }
}

// ---------------- rmsnorm (bf16 in) + re-quantize -> int8 ----------------
__global__ __launch_bounds__(256) void k_rmsnorm_quant(const unsigned short* __restrict__ ain,
    const float* __restrict__ normw, signed char* __restrict__ x2q, float* __restrict__ xs2)
{
  int row=blockIdx.x, t=threadIdx.x;
  const unsigned short* rp = ain + (long)row*2048;
  u32x4 raw = *reinterpret_cast<const u32x4*>(rp + t*8);
  unsigned short tmp[8];
  *reinterpret_cast<u32x4*>(tmp) = raw;
  float xv[8]; float ss=0.f;
  #pragma unroll
  for (int j=0;j<8;j++){ xv[j]=bf2f(tmp[j]); ss += xv[j]*xv[j]; }
  #pragma unroll
  for (int m=1;m<64;m<<=1) ss += __shfl_xor(ss, m);
  __shared__ float red[4];
  if ((t&63)==0) red[t>>6]=ss;
  __syncthreads();
  float ms = (red[0]+red[1]+red[2]+red[3])*(1.0f/2048.0f) + 1e-6f;
  float rs = 1.0f/sqrtf(ms);
  __syncthreads();
  float4 w0 = *reinterpret_cast<const float4*>(normw + t*8);
  float4 w1 = *reinterpret_cast<const float4*>(normw + t*8 + 4);
  float wv[8] = {w0.x,w0.y,w0.z,w0.w,w1.x,w1.y,w1.z,w1.w};
  float y[8]; float mx=0.f;
  #pragma unroll
  for (int j=0;j<8;j++){ y[j] = xv[j]*rs*wv[j]; mx = fmaxf(mx, fabsf(y[j])); }
  #pragma unroll
  for (int m=1;m<64;m<<=1) mx = fmaxf(mx, __shfl_xor(mx, m));
  __shared__ float red2[4];
  if ((t&63)==0) red2[t>>6]=mx;
  __syncthreads();
  float sc = fmaxf(fmaxf(fmaxf(red2[0],red2[1]),fmaxf(red2[2],red2[3])), 1e-5f);
  if (t==0) xs2[row]=sc;
  signed char q[8];
  #pragma unroll
  for (int j=0;j<8;j++) q[j] = (signed char)(int)rintf((y[j]/sc)*127.f);
  *reinterpret_cast<uint2*>(x2q + (long)row*2048 + t*8) = *reinterpret_cast<uint2*>(q);
}

// ---------------- host launch ----------------
extern "C" void kernel_launch(void* const* d_in, const int* in_sizes, int n_in,
                              void* d_out, int out_size, void* d_ws, size_t ws_size,
                              hipStream_t stream)
{
  const float* x      = (const float*)d_in[0];
  const float* qkv_w  = (const float*)d_in[1];
  const float* qkv_b  = (const float*)d_in[2];
  const float* gate_w = (const float*)d_in[3];
  const float* gate_b = (const float*)d_in[4];
  const float* proj_w = (const float*)d_in[5];
  const float* proj_b = (const float*)d_in[6];
  const float* norm_w = (const float*)d_in[7];
  (void)in_sizes; (void)n_in; (void)out_size; (void)ws_size;

  char* ws = (char*)d_ws;
  const size_t MB = 1024UL*1024UL;
  // wq_qkv and wq_gate CONTIGUOUS (merged GEMM reads rows 0..8191)
  signed char* wq_proj = (signed char*)(ws + 0*MB);   // 4MB, alive to end
  signed char* wq_qkv  = (signed char*)(ws + 4*MB);   // 12MB (rows 0..6143)
  signed char* wq_gate = (signed char*)(ws + 16*MB);  // 4MB  (rows 6144..8191)
  signed char* xq      = (signed char*)(ws + 20*MB);  // 16MB, dies after merged gemm
  float*       upds    = (float*)(ws + 4*MB);         // 64MB f32 (1024 slabs), aliases wq_qkv/gate/xq
  unsigned short* qb   = (unsigned short*)(ws + 68*MB);   // 32MB (x2q aliases after B3)
  unsigned short* kb   = (unsigned short*)(ws + 100*MB);  // 32MB
  unsigned short* vb   = (unsigned short*)(ws + 132*MB);  // 32MB
  unsigned short* aof  = (unsigned short*)(ws + 164*MB);  // 32MB bf16
  signed char* x2q     = (signed char*)qb;
  float* xs       = (float*)(ws + 196*MB);
  float* xs2      = xs + 8192;
  float* decay    = xs2 + 8192;
  float* partials = decay + 131072;
  float* scales   = partials + 5120;

  k_quant_all<<<13312,256,0,stream>>>(qkv_w, gate_w, proj_w, x,
      wq_qkv, wq_gate, wq_proj, xq, xs, partials);
  k_finalize<<<1,256,0,stream>>>(partials, scales);
  k_gemm<0,64><<<4096,256,0,stream>>>(xq, wq_qkv, xs, scales, qkv_b, gate_b,
      qb,kb,vb, decay, nullptr);
  k_attnA<<<2048,256,0,stream>>>(qb,kb,vb, aof);
  k_updB1<<<1024,256,0,stream>>>(kb, vb, upds);
  k_scanB2<<<256,256,0,stream>>>(upds, decay);
  k_recurB3<<<1024,256,0,stream>>>(qb, upds, aof);
  k_rmsnorm_quant<<<8192,256,0,stream>>>(aof, norm_w, x2q, xs2);
  k_gemm<2,16><<<1024,256,0,stream>>>(x2q, wq_proj, xs2, scales, proj_b, nullptr,
      nullptr,nullptr,nullptr, nullptr, (float*)d_out);
}

// Round 16
// 381.793 us; speedup vs baseline: 1.0592x; 1.0231x over previous
//
#include <hip/hip_runtime.h>
#include <stdint.h>

typedef __attribute__((ext_vector_type(4))) float f32x4;
typedef __attribute__((ext_vector_type(8))) __bf16 bf16x8;
typedef __attribute__((ext_vector_type(4))) unsigned int u32x4;
typedef __attribute__((ext_vector_type(4))) int i32x4;

#define DEV static __device__ __forceinline__

DEV float bf2f(unsigned short h){ union{unsigned int u; float f;} v; v.u=((unsigned int)h)<<16; return v.f; }
DEV unsigned short f2bf(float f){ union{float ff; unsigned int u;} v; v.ff=f; unsigned int u=v.u;
  u += 0x7fffu + ((u>>16)&1u); return (unsigned short)(u>>16); }

DEV f32x4 mfma16(bf16x8 a, bf16x8 b, f32x4 c){
  return __builtin_amdgcn_mfma_f32_16x16x32_bf16(a, b, c, 0, 0, 0);
}
DEV i32x4 mfma_i8(i32x4 a, i32x4 b, i32x4 c){
  return __builtin_amdgcn_mfma_i32_16x16x64_i8(a, b, c, 0, 0, 0);
}

// async global->LDS, 16B per lane; lds dest = wave-uniform base + lane*16B
#define GLOAD_LDS16(gptr, ldsptr) \
  __builtin_amdgcn_global_load_lds( \
      (const __attribute__((address_space(1))) unsigned int*)(gptr), \
      (__attribute__((address_space(3))) unsigned int*)(ldsptr), 16, 0, 0)

// ---------------- fused quantization: weights (blocks 0..5119) + activations (5120..13311) ----------------
__global__ __launch_bounds__(256) void k_quant_all(
    const float* __restrict__ wq, const float* __restrict__ wg, const float* __restrict__ wp,
    const float* __restrict__ x,
    signed char* __restrict__ oq, signed char* __restrict__ og, signed char* __restrict__ op,
    signed char* __restrict__ xq, float* __restrict__ xs,
    float* __restrict__ partials)
{
  int blk = blockIdx.x, t = threadIdx.x;
  if (blk < 5120){
    const float* src; signed char* dst; long base;
    if (blk < 3072){ src=wq; dst=oq; base=(long)blk*4096; }
    else if (blk < 4096){ src=wg; dst=og; base=(long)(blk-3072)*4096; }
    else { src=wp; dst=op; base=(long)(blk-4096)*4096; }
    float s = 0.f;
    #pragma unroll
    for (int i=0;i<4;i++){
      long e = base + (long)(i*256 + t)*4;
      float4 v = *reinterpret_cast<const float4*>(src + e);
      s += fabsf(v.x)+fabsf(v.y)+fabsf(v.z)+fabsf(v.w);
      signed char tmp[4];
      tmp[0] = (v.x>0.f)?1:((v.x<0.f)?-1:0);
      tmp[1] = (v.y>0.f)?1:((v.y<0.f)?-1:0);
      tmp[2] = (v.z>0.f)?1:((v.z<0.f)?-1:0);
      tmp[3] = (v.w>0.f)?1:((v.w<0.f)?-1:0);
      *reinterpret_cast<unsigned int*>(dst + e) = *reinterpret_cast<unsigned int*>(tmp);
    }
    #pragma unroll
    for (int m=1;m<64;m<<=1) s += __shfl_xor(s, m);
    __shared__ float red[4];
    if ((t&63)==0) red[t>>6]=s;
    __syncthreads();
    if (t==0) partials[blk] = red[0]+red[1]+red[2]+red[3];
  } else {
    int row = blk - 5120;
    const float* xr = x + (long)row*2048;
    float v[8];
    float4 a = *reinterpret_cast<const float4*>(xr + t*8);
    float4 b = *reinterpret_cast<const float4*>(xr + t*8 + 4);
    v[0]=a.x; v[1]=a.y; v[2]=a.z; v[3]=a.w; v[4]=b.x; v[5]=b.y; v[6]=b.z; v[7]=b.w;
    float mx=0.f;
    #pragma unroll
    for (int j=0;j<8;j++) mx = fmaxf(mx, fabsf(v[j]));
    #pragma unroll
    for (int m=1;m<64;m<<=1) mx = fmaxf(mx, __shfl_xor(mx, m));
    __shared__ float red2[4];
    if ((t&63)==0) red2[t>>6]=mx;
    __syncthreads();
    float sc = fmaxf(fmaxf(fmaxf(red2[0],red2[1]),fmaxf(red2[2],red2[3])), 1e-5f);
    if (t==0) xs[row]=sc;
    signed char q[8];
    #pragma unroll
    for (int j=0;j<8;j++) q[j] = (signed char)(int)rintf((v[j]/sc)*127.f);
    *reinterpret_cast<uint2*>(xq + (long)row*2048 + t*8) = *reinterpret_cast<uint2*>(q);
  }
}

__global__ void k_finalize(const float* __restrict__ partials, float* __restrict__ scales)
{
  int t = threadIdx.x;
  __shared__ float red[4];
  for (int w=0; w<3; w++){
    int s0 = (w==0)?0:((w==1)?3072:4096);
    int s1 = (w==0)?3072:((w==1)?4096:5120);
    float acc = 0.f;
    for (int i=s0+t; i<s1; i+=256) acc += partials[i];
    #pragma unroll
    for (int m=1;m<64;m<<=1) acc += __shfl_xor(acc, m);
    if ((t&63)==0) red[t>>6]=acc;
    __syncthreads();
    if (t==0){
      float total = red[0]+red[1]+red[2]+red[3];
      float denom = (w==0)? 12582912.0f : 4194304.0f;
      float wsc = fmaxf(total/denom, 1e-5f);
      scales[w] = wsc / 127.0f;           // folded w_scale/127
    }
    __syncthreads();
  }
}

// ---------------- bitlinear GEMM, int8 MFMA (exact), 128x128 tile, BK=128 ----------------
// round-12 measured-best pipeline with hoisted incrementing source pointers and
// precomputed fragment offsets (test: is VALUBusy=45% address recomputation?).
// MODE 0: merged qkv+gate (bn<48 qkv, else gate/decay); MODE 2: proj -> f32
template<int MODE, int NBN>
__global__ __launch_bounds__(256) void k_gemm(
    const signed char* __restrict__ A, const signed char* __restrict__ Bw,
    const float* __restrict__ xs, const float* __restrict__ scales,
    const float* __restrict__ bias0, const float* __restrict__ bias1,
    unsigned short* __restrict__ oq, unsigned short* __restrict__ ok, unsigned short* __restrict__ ov,
    float* __restrict__ decay, float* __restrict__ of32)
{
  __shared__ signed char As[2][128*128];
  __shared__ signed char Bs[2][128*128];
  const int K = 2048, NT = 16;          // K-tiles of 128
  int tid=threadIdx.x;
  // block swizzle: XCD-contiguous chunks, then 8x8 (bn,bm) super-tiles
  const int nwg = NBN*64, cpx = nwg>>3;
  int wg  = ((int)blockIdx.x & 7)*cpx + ((int)blockIdx.x >> 3);
  int super = wg >> 6, inner = wg & 63;
  int bn = (super % (NBN>>3))*8 + (inner & 7);
  int bm = (super / (NBN>>3))*8 + (inner >> 3);
  long n0=(long)bn*128, m0=(long)bm*128;
  int wave=tid>>6, lane=tid&63, l15=lane&15, l4=lane>>4;
  int wr=wave>>1, wc=wave&1;
  int srow = wave*8 + (lane>>3);                  // staging row within 32-row group
  int scol = ((lane&7) ^ ((lane>>3)&7))*16;       // pre-swizzled source col (bytes)
  i32x4 z4 = {0,0,0,0};
  i32x4 acc[4][4];
  #pragma unroll
  for (int i=0;i<4;i++)
    #pragma unroll
    for (int j=0;j<4;j++) acc[i][j]=z4;

  // hoisted global source pointers, advanced by 128 B per staged tile
  const signed char *gA0 = A  + (m0 +  0 + srow)*K + scol;
  const signed char *gA1 = A  + (m0 + 32 + srow)*K + scol;
  const signed char *gA2 = A  + (m0 + 64 + srow)*K + scol;
  const signed char *gA3 = A  + (m0 + 96 + srow)*K + scol;
  const signed char *gB0 = Bw + (n0 +  0 + srow)*K + scol;
  const signed char *gB1 = Bw + (n0 + 32 + srow)*K + scol;
  const signed char *gB2 = Bw + (n0 + 64 + srow)*K + scol;
  const signed char *gB3 = Bw + (n0 + 96 + srow)*K + scol;

  // precomputed fragment byte-offsets (per mr/nr x kk), buf toggle adds 16384
  int roA[4][2], roB[4][2];
  #pragma unroll
  for (int r=0;r<4;r++)
    #pragma unroll
    for (int kk=0;kk<2;kk++){
      int g = (((kk*4+l4) ^ (l15&7))<<4);
      roA[r][kk] = (wr*64+r*16+l15)*128 + g;
      roB[r][kk] = (wc*64+r*16+l15)*128 + g;
    }
  const signed char* AsB = &As[0][0];
  const signed char* BsB = &Bs[0][0];

#define STAGE_ALL(buf) do{ \
    GLOAD_LDS16(gA0, &As[buf][(  0 + wave*8)*128]); \
    GLOAD_LDS16(gA1, &As[buf][( 32 + wave*8)*128]); \
    GLOAD_LDS16(gA2, &As[buf][( 64 + wave*8)*128]); \
    GLOAD_LDS16(gA3, &As[buf][( 96 + wave*8)*128]); \
    GLOAD_LDS16(gB0, &Bs[buf][(  0 + wave*8)*128]); \
    GLOAD_LDS16(gB1, &Bs[buf][( 32 + wave*8)*128]); \
    GLOAD_LDS16(gB2, &Bs[buf][( 64 + wave*8)*128]); \
    GLOAD_LDS16(gB3, &Bs[buf][( 96 + wave*8)*128]); \
    gA0+=128; gA1+=128; gA2+=128; gA3+=128; \
    gB0+=128; gB1+=128; gB2+=128; gB3+=128; }while(0)

  // prologue: stage tile 0 -> buf 0
  STAGE_ALL(0);

  #pragma unroll 2
  for (int t=0; t<NT; ++t){
    int c = t&1;
    int bo = c*16384;
    if (t+1 < NT){
      STAGE_ALL(c^1);
      asm volatile("s_waitcnt vmcnt(8)" ::: "memory");  // tile t landed; t+1 in flight
    } else {
      asm volatile("s_waitcnt vmcnt(0)" ::: "memory");
    }
    __builtin_amdgcn_s_barrier();
    __builtin_amdgcn_s_setprio(1);
    #pragma unroll
    for (int kk=0;kk<2;kk++){
      i32x4 af[4], bfr[4];
      #pragma unroll
      for (int mr=0;mr<4;mr++) af[mr] = *reinterpret_cast<const i32x4*>(AsB + bo + roA[mr][kk]);
      #pragma unroll
      for (int nr=0;nr<4;nr++) bfr[nr] = *reinterpret_cast<const i32x4*>(BsB + bo + roB[nr][kk]);
      #pragma unroll
      for (int mr=0;mr<4;mr++)
        #pragma unroll
        for (int nr=0;nr<4;nr++)
          acc[mr][nr] = mfma_i8(af[mr], bfr[nr], acc[mr][nr]);
    }
    __builtin_amdgcn_s_setprio(0);
    if (t+1 < NT) __builtin_amdgcn_s_barrier();   // buf c free for next stage
  }

  if (MODE==0 && bn < 48){
    float fac = scales[0];
    float xsv[4][4];
    #pragma unroll
    for (int mr=0;mr<4;mr++)
      #pragma unroll
      for (int r2=0;r2<4;r2++)
        xsv[mr][r2] = xs[m0 + wr*64 + mr*16 + 4*l4 + r2] * fac;
    int sidx = (int)(n0 >> 11);
    unsigned short* dst = (sidx==0)?oq:((sidx==1)?ok:ov);
    int c0 = (int)(n0 & 2047);
    #pragma unroll
    for (int nr=0;nr<4;nr++){
      int c = c0 + wc*64 + nr*16 + l15;
      float bv = bias0[n0 + wc*64 + nr*16 + l15];
      #pragma unroll
      for (int mr=0;mr<4;mr++)
        #pragma unroll
        for (int r2=0;r2<4;r2++){
          long grow = m0 + wr*64 + mr*16 + 4*l4 + r2;
          dst[grow*2048 + c] = f2bf((float)acc[mr][nr][r2]*xsv[mr][r2] + bv);
        }
    }
  } else if (MODE==0){
    // gate branch: bn in [48,64)
    int bng = bn - 48;
    float fac = scales[1];
    float xsv[4][4];
    #pragma unroll
    for (int mr=0;mr<4;mr++)
      #pragma unroll
      for (int r2=0;r2<4;r2++)
        xsv[mr][r2] = xs[m0 + wr*64 + mr*16 + 4*l4 + r2] * fac;
    float* red = reinterpret_cast<float*>(As);  // buf0 region; final reads were buf1 -> safe
    #pragma unroll
    for (int nr=0;nr<4;nr++){
      float bv = bias1[bng*128 + wc*64 + nr*16 + l15];
      float ssum = 0.f;
      #pragma unroll
      for (int mr=0;mr<4;mr++)
        #pragma unroll
        for (int r2=0;r2<4;r2++){
          float val = (float)acc[mr][nr][r2]*xsv[mr][r2] + bv;
          ssum += 1.f/(1.f + expf(-val));
        }
      ssum += __shfl_xor(ssum, 16);
      ssum += __shfl_xor(ssum, 32);
      if (l4==0) red[wr*128 + wc*64 + nr*16 + l15] = ssum;
    }
    __syncthreads();
    if (tid < 128){
      float d = (red[tid] + red[128+tid]) * (1.0f/128.0f);
      decay[((long)bm*16 + bng)*128 + tid] = d;
    }
  } else {
    float fac = scales[2];
    float xsv[4][4];
    #pragma unroll
    for (int mr=0;mr<4;mr++)
      #pragma unroll
      for (int r2=0;r2<4;r2++)
        xsv[mr][r2] = xs[m0 + wr*64 + mr*16 + 4*l4 + r2] * fac;
    #pragma unroll
    for (int nr=0;nr<4;nr++){
      long c = n0 + wc*64 + nr*16 + l15;
      float bv = bias0[c];
      #pragma unroll
      for (int mr=0;mr<4;mr++)
        #pragma unroll
        for (int r2=0;r2<4;r2++){
          long grow = m0 + wr*64 + mr*16 + 4*l4 + r2;
          of32[grow*2048 + c] = (float)acc[mr][nr][r2]*xsv[mr][r2] + bv;
        }
    }
  }
#undef STAGE_ALL
}

// ---------------- Phase A: per-token 16x16 HEAD-mixing attention ----------------
__global__ __launch_bounds__(256) void k_attnA(const unsigned short* __restrict__ qb,
    const unsigned short* __restrict__ kb, const unsigned short* __restrict__ vb,
    unsigned short* __restrict__ aof)
{
  __shared__ unsigned short at[4][16*32];    // attn, zero-padded g in [16,32)
  __shared__ unsigned short vT[4][128*40];   // v^T [e][g], row stride 40, zero-padded
  int tid=threadIdx.x, wave=tid>>6, lane=tid&63, l15=lane&15, l4=lane>>4;
  const float SCALE = 0.08838834764831845f;

  for (int i=lane;i<16*32;i+=64) at[wave][i]=0;
  for (int i=lane;i<128*40;i+=64) vT[wave][i]=0;

  long token = (long)blockIdx.x*4 + wave;
  long base = token*2048;

  bf16x8 qf[4], kf[4];
  #pragma unroll
  for (int kk=0;kk<4;kk++){
    qf[kk] = *reinterpret_cast<const bf16x8*>(qb + base + l15*128 + kk*32 + l4*8);
    kf[kk] = *reinterpret_cast<const bf16x8*>(kb + base + l15*128 + kk*32 + l4*8);
  }
  {
    int g = lane>>2, e0 = (lane&3)*32;
    #pragma unroll
    for (int j=0;j<4;j++){
      u32x4 vv = *reinterpret_cast<const u32x4*>(vb + base + g*128 + e0 + j*8);
      unsigned short tmp[8];
      *reinterpret_cast<u32x4*>(tmp) = vv;
      #pragma unroll
      for (int t2=0;t2<8;t2++) vT[wave][(e0+j*8+t2)*40 + g] = tmp[t2];
    }
  }

  f32x4 s = {0.f,0.f,0.f,0.f};
  #pragma unroll
  for (int kk=0;kk<4;kk++) s = mfma16(qf[kk], kf[kk], s);

  #pragma unroll
  for (int r2=0;r2<4;r2++){
    float v = s[r2];
    float m = v;
    m = fmaxf(m, __shfl_xor(m,1)); m = fmaxf(m, __shfl_xor(m,2));
    m = fmaxf(m, __shfl_xor(m,4)); m = fmaxf(m, __shfl_xor(m,8));
    float p = expf((v-m)*SCALE);
    float sum = p;
    sum += __shfl_xor(sum,1); sum += __shfl_xor(sum,2);
    sum += __shfl_xor(sum,4); sum += __shfl_xor(sum,8);
    at[wave][(4*l4+r2)*32 + l15] = f2bf(p/sum);
  }
  __syncthreads();

  bf16x8 pa = *reinterpret_cast<const bf16x8*>(&at[wave][l15*32 + l4*8]);
  #pragma unroll
  for (int eb=0;eb<8;eb++){
    bf16x8 vf = *reinterpret_cast<const bf16x8*>(&vT[wave][(eb*16+l15)*40 + l4*8]);
    f32x4 z4 = {0.f,0.f,0.f,0.f};
    f32x4 o = mfma16(pa, vf, z4);
    #pragma unroll
    for (int r2=0;r2<4;r2++)
      aof[base + (long)(4*l4+r2)*128 + eb*16 + l15] = f2bf(o[r2]);
  }
}

// ---------------- Phase B1: per-chunk kv-update upd[e][d] = v^T . k ----------------
__global__ __launch_bounds__(256) void k_updB1(
    const unsigned short* __restrict__ kb, const unsigned short* __restrict__ vb,
    float* __restrict__ upds)
{
  __shared__ unsigned short kT[128*128];
  __shared__ unsigned short vT[128*128];
  int bid=blockIdx.x;
  int ch = bid&31, h=(bid>>5)&15, b=bid>>9;
  int tid=threadIdx.x, wave=tid>>6, lane=tid&63, l15=lane&15, l4=lane>>4;
  long base = ((long)b*4096 + (long)ch*128)*2048 + h*128;

  #pragma unroll
  for (int i=0;i<8;i++){
    int s = tid + i*256;
    int l = s>>4, sl = s&15;
    unsigned short tmp[8];
    u32x4 v1 = *reinterpret_cast<const u32x4*>(kb + base + (long)l*2048 + sl*8);
    *reinterpret_cast<u32x4*>(tmp) = v1;
    #pragma unroll
    for (int j=0;j<8;j++){
      int d = sl*8+j;
      kT[d*128 + (((l>>3)^(d&15))<<3) + (l&7)] = tmp[j];
    }
    u32x4 v2 = *reinterpret_cast<const u32x4*>(vb + base + (long)l*2048 + sl*8);
    *reinterpret_cast<u32x4*>(tmp) = v2;
    #pragma unroll
    for (int j=0;j<8;j++){
      int e = sl*8+j;
      vT[e*128 + (((l>>3)^(e&15))<<3) + (l&7)] = tmp[j];
    }
  }
  __syncthreads();

  f32x4 z4 = {0.f,0.f,0.f,0.f};
  f32x4 acc[2][8];
  #pragma unroll
  for (int er=0;er<2;er++)
    #pragma unroll
    for (int dc=0;dc<8;dc++) acc[er][dc]=z4;

  #pragma unroll
  for (int kk=0;kk<4;kk++){
    bf16x8 xf[2];
    #pragma unroll
    for (int er=0;er<2;er++){
      int e = wave*32 + er*16 + l15;
      xf[er] = *reinterpret_cast<const bf16x8*>(vT + e*128 + (((kk*4+l4)^(e&15))<<3));
    }
    #pragma unroll
    for (int dc=0;dc<8;dc++){
      int d = dc*16 + l15;
      bf16x8 kf = *reinterpret_cast<const bf16x8*>(kT + d*128 + (((kk*4+l4)^(d&15))<<3));
      #pragma unroll
      for (int er=0;er<2;er++)
        acc[er][dc] = mfma16(xf[er], kf, acc[er][dc]);
    }
  }

  float* dst = upds + (long)bid*16384;
  #pragma unroll
  for (int er=0;er<2;er++)
    #pragma unroll
    for (int dc=0;dc<8;dc++)
      #pragma unroll
      for (int r2=0;r2<4;r2++){
        int e = wave*32 + er*16 + 4*l4 + r2;
        int d = dc*16 + l15;
        dst[e*128 + d] = acc[er][dc][r2];
      }
}

// ---------------- Phase B2: in-place elementwise scan over chunks ----------------
__global__ __launch_bounds__(256) void k_scanB2(float* __restrict__ buf,
    const float* __restrict__ decay)
{
  int bid=blockIdx.x;
  int strip = bid&7, bh = bid>>3;
  int b = bh>>4, h = bh&15;
  int t = threadIdx.x;
  int f0 = t, f1 = t + 256;
  int e0 = strip*16 + (f0>>5), d0 = (f0&31)*4;
  int e1 = strip*16 + (f1>>5);
  long base = (long)bh * 32 * 16384;
  long o0 = (long)e0*128 + d0;
  long o1 = (long)e1*128 + d0;
  float4 s0 = {0.f,0.f,0.f,0.f}, s1 = {0.f,0.f,0.f,0.f};
  for (int ch=0; ch<32; ch++){
    float* p = buf + base + (long)ch*16384;
    float4 u0 = *reinterpret_cast<float4*>(p + o0);
    float4 u1 = *reinterpret_cast<float4*>(p + o1);
    *reinterpret_cast<float4*>(p + o0) = s0;
    *reinterpret_cast<float4*>(p + o1) = s1;
    float4 dc = *reinterpret_cast<const float4*>(decay + ((long)(b*32+ch)*16 + h)*128 + d0);
    s0.x = s0.x*dc.x + u0.x; s0.y = s0.y*dc.y + u0.y;
    s0.z = s0.z*dc.z + u0.z; s0.w = s0.w*dc.w + u0.w;
    s1.x = s1.x*dc.x + u1.x; s1.y = s1.y*dc.y + u1.y;
    s1.z = s1.z*dc.z + u1.z; s1.w = s1.w*dc.w + u1.w;
  }
}

// ---------------- Phase B3: recur[l][e] = q . state[e][:], hi/lo split, RMW aof ----------------
__global__ __launch_bounds__(256) void k_recurB3(
    const unsigned short* __restrict__ qb, const float* __restrict__ upds,
    unsigned short* __restrict__ aof)
{
  __shared__ unsigned short sh[128*128];
  __shared__ unsigned short slo[128*128];
  int bid=blockIdx.x;
  int ch = bid&31, h=(bid>>5)&15, b=bid>>9;
  int tid=threadIdx.x, wave=tid>>6, lane=tid&63, l15=lane&15, l4=lane>>4;
  long slab = (long)bid*16384;
  long base = ((long)b*4096 + (long)ch*128)*2048 + h*128;

  #pragma unroll
  for (int i=0;i<8;i++){
    int s = tid + i*256;
    int e = s>>4, sl = s&15;
    float4 a = *reinterpret_cast<const float4*>(upds + slab + (long)e*128 + sl*8);
    float4 c = *reinterpret_cast<const float4*>(upds + slab + (long)e*128 + sl*8 + 4);
    float vv[8] = {a.x,a.y,a.z,a.w,c.x,c.y,c.z,c.w};
    unsigned short hi[8], lo[8];
    #pragma unroll
    for (int j=0;j<8;j++){
      hi[j] = f2bf(vv[j]);
      lo[j] = f2bf(vv[j] - bf2f(hi[j]));
    }
    int slot = e*128 + ((sl ^ (e&15))<<3);
    *reinterpret_cast<u32x4*>(sh + slot)  = *reinterpret_cast<u32x4*>(hi);
    *reinterpret_cast<u32x4*>(slo + slot) = *reinterpret_cast<u32x4*>(lo);
  }

  bf16x8 qf[2][4];
  #pragma unroll
  for (int mr=0;mr<2;mr++)
    #pragma unroll
    for (int kk=0;kk<4;kk++)
      qf[mr][kk] = *reinterpret_cast<const bf16x8*>(qb + base + (long)(wave*32+mr*16+l15)*2048 + kk*32 + l4*8);
  __syncthreads();

  f32x4 z4 = {0.f,0.f,0.f,0.f};
  f32x4 acc[2][8];
  #pragma unroll
  for (int mr=0;mr<2;mr++)
    #pragma unroll
    for (int ec=0;ec<8;ec++) acc[mr][ec]=z4;

  #pragma unroll
  for (int kk=0;kk<4;kk++)
    #pragma unroll
    for (int ec=0;ec<8;ec++){
      int e = ec*16 + l15;
      int slot = (((kk*4+l4)^(e&15))<<3);
      bf16x8 tfh = *reinterpret_cast<const bf16x8*>(sh + e*128 + slot);
      bf16x8 tfl = *reinterpret_cast<const bf16x8*>(slo + e*128 + slot);
      #pragma unroll
      for (int mr=0;mr<2;mr++){
        acc[mr][ec] = mfma16(qf[mr][kk], tfh, acc[mr][ec]);
        acc[mr][ec] = mfma16(qf[mr][kk], tfl, acc[mr][ec]);
      }
    }

  #pragma unroll
  for (int mr=0;mr<2;mr++)
    #pragma unroll
    for (int ec=0;ec<8;ec++)
      #pragma unroll
      for (int r2=0;r2<4;r2++){
        long o = base + (long)(wave*32+mr*16+4*l4+r2)*2048 + ec*16 + l15;
        aof[o] = f2bf(bf2f(aof[o]) + acc[mr][ec][r2]);
      }
}

// ---------------- rmsnorm (bf16 in) + re-quantize -> int8 ----------------
__global__ __launch_bounds__(256) void k_rmsnorm_quant(const unsigned short* __restrict__ ain,
    const float* __restrict__ normw, signed char* __restrict__ x2q, float* __restrict__ xs2)
{
  int row=blockIdx.x, t=threadIdx.x;
  const unsigned short* rp = ain + (long)row*2048;
  u32x4 raw = *reinterpret_cast<const u32x4*>(rp + t*8);
  unsigned short tmp[8];
  *reinterpret_cast<u32x4*>(tmp) = raw;
  float xv[8]; float ss=0.f;
  #pragma unroll
  for (int j=0;j<8;j++){ xv[j]=bf2f(tmp[j]); ss += xv[j]*xv[j]; }
  #pragma unroll
  for (int m=1;m<64;m<<=1) ss += __shfl_xor(ss, m);
  __shared__ float red[4];
  if ((t&63)==0) red[t>>6]=ss;
  __syncthreads();
  float ms = (red[0]+red[1]+red[2]+red[3])*(1.0f/2048.0f) + 1e-6f;
  float rs = 1.0f/sqrtf(ms);
  __syncthreads();
  float4 w0 = *reinterpret_cast<const float4*>(normw + t*8);
  float4 w1 = *reinterpret_cast<const float4*>(normw + t*8 + 4);
  float wv[8] = {w0.x,w0.y,w0.z,w0.w,w1.x,w1.y,w1.z,w1.w};
  float y[8]; float mx=0.f;
  #pragma unroll
  for (int j=0;j<8;j++){ y[j] = xv[j]*rs*wv[j]; mx = fmaxf(mx, fabsf(y[j])); }
  #pragma unroll
  for (int m=1;m<64;m<<=1) mx = fmaxf(mx, __shfl_xor(mx, m));
  __shared__ float red2[4];
  if ((t&63)==0) red2[t>>6]=mx;
  __syncthreads();
  float sc = fmaxf(fmaxf(fmaxf(red2[0],red2[1]),fmaxf(red2[2],red2[3])), 1e-5f);
  if (t==0) xs2[row]=sc;
  signed char q[8];
  #pragma unroll
  for (int j=0;j<8;j++) q[j] = (signed char)(int)rintf((y[j]/sc)*127.f);
  *reinterpret_cast<uint2*>(x2q + (long)row*2048 + t*8) = *reinterpret_cast<uint2*>(q);
}

// ---------------- host launch ----------------
extern "C" void kernel_launch(void* const* d_in, const int* in_sizes, int n_in,
                              void* d_out, int out_size, void* d_ws, size_t ws_size,
                              hipStream_t stream)
{
  const float* x      = (const float*)d_in[0];
  const float* qkv_w  = (const float*)d_in[1];
  const float* qkv_b  = (const float*)d_in[2];
  const float* gate_w = (const float*)d_in[3];
  const float* gate_b = (const float*)d_in[4];
  const float* proj_w = (const float*)d_in[5];
  const float* proj_b = (const float*)d_in[6];
  const float* norm_w = (const float*)d_in[7];
  (void)in_sizes; (void)n_in; (void)out_size; (void)ws_size;

  char* ws = (char*)d_ws;
  const size_t MB = 1024UL*1024UL;
  // wq_qkv and wq_gate CONTIGUOUS (merged GEMM reads rows 0..8191)
  signed char* wq_proj = (signed char*)(ws + 0*MB);   // 4MB, alive to end
  signed char* wq_qkv  = (signed char*)(ws + 4*MB);   // 12MB (rows 0..6143)
  signed char* wq_gate = (signed char*)(ws + 16*MB);  // 4MB  (rows 6144..8191)
  signed char* xq      = (signed char*)(ws + 20*MB);  // 16MB, dies after merged gemm
  float*       upds    = (float*)(ws + 4*MB);         // 64MB f32 (1024 slabs), aliases wq_qkv/gate/xq
  unsigned short* qb   = (unsigned short*)(ws + 68*MB);   // 32MB (x2q aliases after B3)
  unsigned short* kb   = (unsigned short*)(ws + 100*MB);  // 32MB
  unsigned short* vb   = (unsigned short*)(ws + 132*MB);  // 32MB
  unsigned short* aof  = (unsigned short*)(ws + 164*MB);  // 32MB bf16
  signed char* x2q     = (signed char*)qb;
  float* xs       = (float*)(ws + 196*MB);
  float* xs2      = xs + 8192;
  float* decay    = xs2 + 8192;
  float* partials = decay + 131072;
  float* scales   = partials + 5120;

  k_quant_all<<<13312,256,0,stream>>>(qkv_w, gate_w, proj_w, x,
      wq_qkv, wq_gate, wq_proj, xq, xs, partials);
  k_finalize<<<1,256,0,stream>>>(partials, scales);
  k_gemm<0,64><<<4096,256,0,stream>>>(xq, wq_qkv, xs, scales, qkv_b, gate_b,
      qb,kb,vb, decay, nullptr);
  k_attnA<<<2048,256,0,stream>>>(qb,kb,vb, aof);
  k_updB1<<<1024,256,0,stream>>>(kb, vb, upds);
  k_scanB2<<<256,256,0,stream>>>(upds, decay);
  k_recurB3<<<1024,256,0,stream>>>(qb, upds, aof);
  k_rmsnorm_quant<<<8192,256,0,stream>>>(aof, norm_w, x2q, xs2);
  k_gemm<2,16><<<1024,256,0,stream>>>(x2q, wq_proj, xs2, scales, proj_b, nullptr,
      nullptr,nullptr,nullptr, nullptr, (float*)d_out);
}